// Round 10
// baseline (230.436 us; speedup 1.0000x reference)
//
#include <hip/hip_runtime.h>

typedef unsigned short u16;
typedef short bf16x8 __attribute__((ext_vector_type(8)));   // 8 bf16 = 4 VGPR
typedef float floatx4 __attribute__((ext_vector_type(4)));

#define LSEQ 2048
#define BB 8
#define NTOK (LSEQ*BB)        // 16384 tokens, n = l*B + b
#define DMODEL 256
#define DINNER 512
#define NSEG 128              // legacy workspace sizing only
#define SEG_N 64              // segments used by scan/stitch
#define SEG_L 32              // LSEQ / SEG_N

__device__ __forceinline__ float siluf(float x){ return x / (1.f + __expf(-x)); }
__device__ __forceinline__ float b2f(u16 x){ return __uint_as_float(((unsigned)x) << 16); }
__device__ __forceinline__ u16 f2b(float f){
  unsigned u = __float_as_uint(f);
  unsigned r = (u + 0x7fffu + ((u >> 16) & 1u)) >> 16;
  return (u16)r;
}

// async global->LDS, 16B per lane; LDS dest is wave-uniform base + lane*16B.
__device__ __forceinline__ void gload16(const u16* g, u16* l) {
  __builtin_amdgcn_global_load_lds(
      (const __attribute__((address_space(1))) unsigned int*)g,
      (__attribute__((address_space(3))) unsigned int*)l, 16, 0, 0);
}

// dA powers: uni fast path (A_s = (s+1)*A_0) needs only As0; fallback re-reads Alog.
__device__ __forceinline__ void compute_dA(float dt, float As0, bool uni,
    const float* __restrict__ Alog, int c, float* dA)
{
  if (uni) {
    float p = __expf(dt*As0);
    float p2 = p*p, p4 = p2*p2, p8 = p4*p4;
    dA[0]=p;      dA[1]=p2;     dA[2]=p2*p;   dA[3]=p4;
    dA[4]=p4*p;   dA[5]=p4*p2;  dA[6]=p4*p2*p;dA[7]=p8;
    dA[8]=p8*p;   dA[9]=p8*p2;  dA[10]=p8*p2*p; dA[11]=p8*p4;
    dA[12]=p8*p4*p; dA[13]=p8*p4*p2; dA[14]=p8*p4*p2*p; dA[15]=p8*p8;
  } else {
    #pragma unroll
    for (int s = 0; s < 16; ++s) dA[s] = __expf(dt * (-__expf(Alog[c*16+s])));
  }
}

// ---------------- prep: weight transpose/casts (tiled for the two big ones)
__global__ __launch_bounds__(256) void prep_k(
    const float* __restrict__ Wemb, const float* __restrict__ Win,
    const float* __restrict__ Wout, const float* __restrict__ Wx,
    const float* __restrict__ Wh,
    u16* __restrict__ WTe, u16* __restrict__ WTi, u16* __restrict__ WTo,
    u16* __restrict__ WxT, u16* __restrict__ WhT)
{
  __shared__ u16 T[64*66];
  int g = blockIdx.x, tid = threadIdx.x;
  if (g < 96) {                         // tiled transposes
    const float* src; u16* dst; int n0, k0, srcld, dstld;
    if (g < 64) {                       // WTi[n][k] = Win[k*1024+n], n<1024,k<256
      int tn = g & 15, tk = g >> 4;
      n0 = tn*64; k0 = tk*64; src = Win; dst = WTi; srcld = 1024; dstld = 256;
    } else {                            // WTo[n][k] = Wout[k*256+n], n<256,k<512
      int g2 = g - 64;
      int tn = g2 & 3, tk = g2 >> 2;
      n0 = tn*64; k0 = tk*64; src = Wout; dst = WTo; srcld = 256; dstld = 512;
    }
    int rr = tid >> 6, cc = tid & 63;
    #pragma unroll
    for (int p = 0; p < 16; ++p) {
      int kr = p*4 + rr;
      T[kr*66 + cc] = f2b(src[(size_t)(k0+kr)*srcld + n0 + cc]);
    }
    __syncthreads();
    #pragma unroll
    for (int p = 0; p < 16; ++p) {
      int nr = p*4 + rr;
      dst[(size_t)(n0+nr)*dstld + k0 + cc] = T[cc*66 + nr];
    }
  } else if (g < 224) {                 // WTe[n][k], n<256, k<128
    int idx = (g-96)*256 + tid; int n = idx >> 7, k = idx & 127;
    WTe[idx] = f2b(Wemb[(size_t)k*256 + n]);
  } else if (g < 320) {                 // WxT[48][512]
    int idx = (g-224)*256 + tid; int n = idx >> 9, k = idx & 511;
    WxT[idx] = f2b(Wx[(size_t)k*48 + n]);
  } else {                              // WhT[32][256]
    int idx = (g-320)*256 + tid; int j = idx >> 8, k = idx & 255;
    WhT[idx] = f2b(Wh[(size_t)k*32 + j]);
  }
}

// ---------------- fused emb GEMM + RMSNorm: block = 64 tokens x full N=256.
__global__ __launch_bounds__(256) void embnorm_k(
    const float* __restrict__ s, const u16* __restrict__ WTe,
    const float* __restrict__ bemb, const float* __restrict__ nw,
    u16* __restrict__ Xb, u16* __restrict__ XNb)
{
  __shared__ u16 SH[64*264];
  __shared__ float ssq[64*4];
  __shared__ float rr[64];
  u16* As = SH;
  u16* Bs = SH + 64*40;
  const int tid = threadIdx.x;
  const int wave = tid >> 6, lane = tid & 63;
  const int quad = lane >> 4, l16 = lane & 15;
  const int m0 = blockIdx.x*64;
  const int wn = wave*64;
  const int srow = tid >> 2, sch = (tid & 3)*8;
  floatx4 acc[4][4];
  #pragma unroll
  for (int r = 0; r < 4; ++r)
    #pragma unroll
    for (int c = 0; c < 4; ++c) acc[r][c] = (floatx4){0.f,0.f,0.f,0.f};

  for (int k0 = 0; k0 < 128; k0 += 32) {
    {
      float4 v0 = *(const float4*)&s[(size_t)(m0+srow)*128 + k0 + sch];
      float4 v1 = *(const float4*)&s[(size_t)(m0+srow)*128 + k0 + sch + 4];
      __align__(16) u16 o[8];
      o[0]=f2b(v0.x); o[1]=f2b(v0.y); o[2]=f2b(v0.z); o[3]=f2b(v0.w);
      o[4]=f2b(v1.x); o[5]=f2b(v1.y); o[6]=f2b(v1.z); o[7]=f2b(v1.w);
      *(uint4*)&As[srow*40 + sch] = *(const uint4*)o;
    }
    #pragma unroll
    for (int p = 0; p < 4; ++p) {
      int row = srow + p*64;
      *(uint4*)&Bs[row*40 + sch] = *(const uint4*)&WTe[(size_t)row*128 + k0 + sch];
    }
    __syncthreads();
    bf16x8 af[4], bf[4];
    #pragma unroll
    for (int r = 0; r < 4; ++r) af[r] = *(const bf16x8*)&As[(r*16 + l16)*40 + quad*8];
    #pragma unroll
    for (int c = 0; c < 4; ++c) bf[c] = *(const bf16x8*)&Bs[(wn + c*16 + l16)*40 + quad*8];
    #pragma unroll
    for (int r = 0; r < 4; ++r)
      #pragma unroll
      for (int c = 0; c < 4; ++c)
        acc[r][c] = __builtin_amdgcn_mfma_f32_16x16x32_bf16(af[r], bf[c], acc[r][c], 0, 0, 0);
    __syncthreads();
  }
  u16* Xs = SH;                         // [64][264]
  #pragma unroll
  for (int c = 0; c < 4; ++c) {
    int n = wn + c*16 + l16;
    float bv = bemb[n];
    #pragma unroll
    for (int r = 0; r < 4; ++r)
      #pragma unroll
      for (int reg = 0; reg < 4; ++reg) {
        int ml = r*16 + quad*4 + reg;
        Xs[ml*264 + n] = f2b(acc[r][c][reg] + bv);
      }
  }
  __syncthreads();
  #pragma unroll
  for (int p = 0; p < 8; ++p) {
    int row = p*8 + (tid >> 5);
    int col = (tid & 31)*8;
    *(uint4*)&Xb[(size_t)(m0+row)*256 + col] = *(const uint4*)&Xs[row*264 + col];
  }
  const int tk = tid >> 2, q = tid & 3;
  float ss = 0.f;
  #pragma unroll
  for (int j = 0; j < 8; ++j) {
    uint4 v = *(const uint4*)&Xs[tk*264 + q*64 + j*8];
    const u16* u = (const u16*)&v;
    #pragma unroll
    for (int i = 0; i < 8; ++i) { float x = b2f(u[i]); ss += x*x; }
  }
  ssq[tk*4 + q] = ss;
  __syncthreads();
  if (q == 0)
    rr[tk] = rsqrtf((ssq[tk*4]+ssq[tk*4+1]+ssq[tk*4+2]+ssq[tk*4+3])*(1.f/DMODEL) + 1e-5f);
  __syncthreads();
  float r = rr[tk];
  #pragma unroll
  for (int j = 0; j < 8; ++j) {
    int idx = q*64 + j*8;
    uint4 v = *(const uint4*)&Xs[tk*264 + idx];
    const u16* u = (const u16*)&v;
    float4 w0 = *(const float4*)&nw[idx];
    float4 w1 = *(const float4*)&nw[idx+4];
    __align__(16) u16 o[8];
    o[0]=f2b(b2f(u[0])*r*w0.x); o[1]=f2b(b2f(u[1])*r*w0.y);
    o[2]=f2b(b2f(u[2])*r*w0.z); o[3]=f2b(b2f(u[3])*r*w0.w);
    o[4]=f2b(b2f(u[4])*r*w1.x); o[5]=f2b(b2f(u[5])*r*w1.y);
    o[6]=f2b(b2f(u[6])*r*w1.z); o[7]=f2b(b2f(u[7])*r*w1.w);
    *(uint4*)&XNb[(size_t)(m0+tk)*256 + idx] = *(const uint4*)o;
  }
}

// ---------------- in-proj GEMM, BK=64, global_load_lds staging + XOR-swizzled
// LDS (linear dest, inverse-swizzled source, swizzled ds_read — rule #21).
template<int K>
__global__ __launch_bounds__(256) void gemm_mfma(
    const u16* __restrict__ Ab, const u16* __restrict__ WT,
    u16* __restrict__ Cv, int N)
{
  __shared__ __align__(16) u16 SH[17408];   // staging 2*128*64=16384; Cs 128*136
  u16* As = SH;
  u16* Bs = SH + 128*64;
  const int tid = threadIdx.x;
  const int wave = tid >> 6, lane = tid & 63;
  const int quad = lane >> 4, l16 = lane & 15;
  const int bm0 = blockIdx.x*128, bn0 = blockIdx.y*128;
  const int wm = (wave & 1)*64, wn = (wave >> 1)*64;
  floatx4 acc[4][4];
  #pragma unroll
  for (int r = 0; r < 4; ++r)
    #pragma unroll
    for (int c = 0; c < 4; ++c) acc[r][c] = (floatx4){0.f,0.f,0.f,0.f};

  for (int k0 = 0; k0 < K; k0 += 64) {
    #pragma unroll
    for (int p = 0; p < 4; ++p) {
      int cid = (wave*4 + p)*64 + lane;
      int row = cid >> 3, sch = (cid & 7) ^ (row & 7);
      gload16(&Ab[(size_t)(bm0+row)*K + k0 + sch*8], As + (wave*4+p)*512);
      gload16(&WT[(size_t)(bn0+row)*K + k0 + sch*8], Bs + (wave*4+p)*512);
    }
    __syncthreads();
    #pragma unroll
    for (int ks = 0; ks < 2; ++ks) {
      bf16x8 af[4], bf[4];
      #pragma unroll
      for (int r = 0; r < 4; ++r) {
        int row = wm + r*16 + l16;
        int lch = (ks*4 + quad) ^ (row & 7);
        af[r] = *(const bf16x8*)&As[row*64 + lch*8];
      }
      #pragma unroll
      for (int c = 0; c < 4; ++c) {
        int row = wn + c*16 + l16;
        int lch = (ks*4 + quad) ^ (row & 7);
        bf[c] = *(const bf16x8*)&Bs[row*64 + lch*8];
      }
      #pragma unroll
      for (int r = 0; r < 4; ++r)
        #pragma unroll
        for (int c = 0; c < 4; ++c)
          acc[r][c] = __builtin_amdgcn_mfma_f32_16x16x32_bf16(af[r], bf[c], acc[r][c], 0, 0, 0);
    }
    __syncthreads();
  }
  u16* Cs = SH;                         // [128][136]
  #pragma unroll
  for (int c = 0; c < 4; ++c) {
    int nl = wn + c*16 + l16;
    #pragma unroll
    for (int r = 0; r < 4; ++r)
      #pragma unroll
      for (int reg = 0; reg < 4; ++reg) {
        int ml = wm + r*16 + quad*4 + reg;
        Cs[ml*136 + nl] = f2b(acc[r][c][reg]);
      }
  }
  __syncthreads();
  #pragma unroll
  for (int p = 0; p < 8; ++p) {
    int row = p*16 + (tid >> 4);
    int col = (tid & 15)*8;
    uint4 v = *(const uint4*)&Cs[row*136 + col];
    *(uint4*)&Cv[(size_t)(bm0+row)*N + bn0 + col] = v;
  }
}

// ---------------- x_dbl GEMM1 with fused causal conv+SiLU in the staging phase.
// Persists conv output xp to XPb so the scans never redo the conv.
__global__ __launch_bounds__(256) void xdblBC_k(const u16* __restrict__ XZb,
    const float* __restrict__ cw, const float* __restrict__ cb,
    const u16* __restrict__ WxT,
    float* __restrict__ BM, float* __restrict__ CM, float* __restrict__ DTR,
    u16* __restrict__ XPb)
{
  __shared__ u16 As[64*40];
  __shared__ u16 Ws[48*40];
  __shared__ float CWs[512*4];
  __shared__ float CBs[512];
  const int tid = threadIdx.x;
  const int wave = tid >> 6, lane = tid & 63;
  const int quad = lane >> 4, l16 = lane & 15;
  const int m0 = blockIdx.x*64;
  const int srow = tid >> 2, sch = (tid & 3)*8;
  const int n = m0 + srow;
  for (int e = tid; e < 2048; e += 256) CWs[e] = cw[e];
  for (int e = tid; e < 512;  e += 256) CBs[e] = cb[e];
  floatx4 acc[3];
  #pragma unroll
  for (int j = 0; j < 3; ++j) acc[j] = (floatx4){0.f,0.f,0.f,0.f};
  __syncthreads();
  const bf16x8 z8 = {0,0,0,0,0,0,0,0};
  for (int k0 = 0; k0 < DINNER; k0 += 32) {
    bf16x8 t3 = *(const bf16x8*)&XZb[(size_t)n*1024 + k0 + sch];
    bf16x8 t2 = z8, t1 = z8, t0v = z8;
    if (n >= 8)  t2  = *(const bf16x8*)&XZb[(size_t)(n-8)*1024  + k0 + sch];
    if (n >= 16) t1  = *(const bf16x8*)&XZb[(size_t)(n-16)*1024 + k0 + sch];
    if (n >= 24) t0v = *(const bf16x8*)&XZb[(size_t)(n-24)*1024 + k0 + sch];
    __align__(16) u16 outa[8];
    #pragma unroll
    for (int j = 0; j < 8; ++j) {
      int c = k0 + sch + j;
      float4 wv = *(const float4*)&CWs[c*4];
      float xc = CBs[c] + wv.x*b2f((u16)t0v[j]) + wv.y*b2f((u16)t1[j])
               + wv.z*b2f((u16)t2[j]) + wv.w*b2f((u16)t3[j]);
      outa[j] = f2b(siluf(xc));
    }
    *(uint4*)&As[srow*40 + sch] = *(const uint4*)outa;
    *(uint4*)&XPb[(size_t)n*DINNER + k0 + sch] = *(const uint4*)outa;
    if (tid < 192) {
      int wr = tid >> 2;
      *(uint4*)&Ws[wr*40 + sch] = *(const uint4*)&WxT[(size_t)wr*512 + k0 + sch];
    }
    __syncthreads();
    bf16x8 af = *(const bf16x8*)&As[(wave*16 + l16)*40 + quad*8];
    #pragma unroll
    for (int j = 0; j < 3; ++j) {
      bf16x8 bf = *(const bf16x8*)&Ws[(j*16 + l16)*40 + quad*8];
      acc[j] = __builtin_amdgcn_mfma_f32_16x16x32_bf16(af, bf, acc[j], 0, 0, 0);
    }
    __syncthreads();
  }
  const int tok0 = m0 + wave*16;
  #pragma unroll
  for (int reg = 0; reg < 4; ++reg) {
    size_t t = (size_t)(tok0 + quad*4 + reg);
    BM[t*16 + l16]  = acc[1][reg];
    CM[t*16 + l16]  = acc[2][reg];
    DTR[t*16 + l16] = acc[0][reg];
  }
}

// ---------------- scan phase A: dt projection inline, xp from XPb (prefetched).
// BM/DTR rows staged in LDS. Stores h_end + sum(dt). (No DXb — scanC recomputes.)
__global__ __launch_bounds__(256) void scanA_k(const float* __restrict__ DTR,
    const u16* __restrict__ XPb, const float* __restrict__ BM,
    const float* __restrict__ Wdt, const float* __restrict__ bdt,
    const float* __restrict__ Alog, u16* __restrict__ HENDb,
    float* __restrict__ DTS)
{
  __shared__ float ROWa[SEG_L*16];      // BM rows
  __shared__ float ROWb[SEG_L*16];      // DTR rows
  const int tid = threadIdx.x;
  const int seg = blockIdx.x, b = blockIdx.y, half = blockIdx.z;
  const int c = half*256 + tid;
  const int t0 = seg*SEG_L;
  const size_t base = (size_t)t0*BB + b;
  for (int idx = tid; idx < SEG_L*16; idx += 256) {
    int t = idx >> 4, j = idx & 15;
    size_t off = (base + (size_t)t*BB)*16 + j;
    ROWa[idx] = BM[off];
    ROWb[idx] = DTR[off];
  }
  float As0 = -__expf(Alog[c*16]);
  bool uni = true;
  #pragma unroll
  for (int s = 1; s < 16; ++s) {
    float Av = -__expf(Alog[c*16+s]);
    uni = uni && (fabsf(Av - As0*(float)(s+1)) <= 1e-4f*(float)(s+1));
  }
  float wdt[16];
  #pragma unroll
  for (int r = 0; r < 16; ++r) wdt[r] = Wdt[r*DINNER + c];
  const float bd = bdt[c];
  float h[16];
  #pragma unroll
  for (int s = 0; s < 16; ++s) h[s] = 0.f;
  float dts = 0.f;
  const u16* xpp = XPb + base*DINNER + c;
  __syncthreads();
  float xp = b2f(xpp[0]);
  for (int t = 0; t < SEG_L; ++t) {
    float xpn = (t+1 < SEG_L) ? b2f(xpp[(size_t)(t+1)*BB*DINNER]) : 0.f;
    float dsum = bd;
    #pragma unroll
    for (int r = 0; r < 16; ++r) dsum = fmaf(ROWb[t*16+r], wdt[r], dsum);
    float dt = (dsum > 20.f) ? dsum : __logf(1.f + __expf(dsum));
    dts += dt;
    float dtx = dt * xp;
    float dA[16];
    compute_dA(dt, As0, uni, Alog, c, dA);
    float4 r0 = *(const float4*)&ROWa[t*16 + 0];
    float4 r1 = *(const float4*)&ROWa[t*16 + 4];
    float4 r2 = *(const float4*)&ROWa[t*16 + 8];
    float4 r3 = *(const float4*)&ROWa[t*16 + 12];
    h[0]  = fmaf(dA[0],  h[0],  dtx*r0.x);
    h[1]  = fmaf(dA[1],  h[1],  dtx*r0.y);
    h[2]  = fmaf(dA[2],  h[2],  dtx*r0.z);
    h[3]  = fmaf(dA[3],  h[3],  dtx*r0.w);
    h[4]  = fmaf(dA[4],  h[4],  dtx*r1.x);
    h[5]  = fmaf(dA[5],  h[5],  dtx*r1.y);
    h[6]  = fmaf(dA[6],  h[6],  dtx*r1.z);
    h[7]  = fmaf(dA[7],  h[7],  dtx*r1.w);
    h[8]  = fmaf(dA[8],  h[8],  dtx*r2.x);
    h[9]  = fmaf(dA[9],  h[9],  dtx*r2.y);
    h[10] = fmaf(dA[10], h[10], dtx*r2.z);
    h[11] = fmaf(dA[11], h[11], dtx*r2.w);
    h[12] = fmaf(dA[12], h[12], dtx*r3.x);
    h[13] = fmaf(dA[13], h[13], dtx*r3.y);
    h[14] = fmaf(dA[14], h[14], dtx*r3.z);
    h[15] = fmaf(dA[15], h[15], dtx*r3.w);
    xp = xpn;
  }
  u16* hp = &HENDb[(((size_t)seg*BB + b)*DINNER + c)*16];
  #pragma unroll
  for (int q = 0; q < 2; ++q) {
    ushort4 v0, v1;
    v0.x = f2b(h[q*8+0]); v0.y = f2b(h[q*8+1]); v0.z = f2b(h[q*8+2]); v0.w = f2b(h[q*8+3]);
    v1.x = f2b(h[q*8+4]); v1.y = f2b(h[q*8+5]); v1.z = f2b(h[q*8+6]); v1.w = f2b(h[q*8+7]);
    *(ushort4*)&hp[q*8]     = v0;
    *(ushort4*)&hp[q*8 + 4] = v1;
  }
  DTS[((size_t)seg*BB + b)*DINNER + c] = dts;
}

// ---------------- stitch: sequential over SEG_N segments, in-place HENDb -> h0.
// Unroll-by-4 with batched prefetch: one load-stall per 4 iterations.
__global__ __launch_bounds__(256) void stitch_k(u16* __restrict__ HENDb,
    const float* __restrict__ DTS, const float* __restrict__ Alog)
{
  int g = blockIdx.x*256 + threadIdx.x;
  int b = g >> 13;
  int rem = g & 8191;          // c*16+s
  int cidx = rem >> 4;
  float A = -__expf(Alog[rem]);
  float h0 = 0.f;
  for (int k = 0; k < SEG_N; k += 4) {
    float he[4], ds[4];
    #pragma unroll
    for (int u = 0; u < 4; ++u) {
      size_t idx = (((size_t)(k+u)*BB + b) << 13) + rem;
      he[u] = b2f(HENDb[idx]);
      ds[u] = DTS[((size_t)(k+u)*BB + b)*DINNER + cidx];
    }
    #pragma unroll
    for (int u = 0; u < 4; ++u) {
      size_t idx = (((size_t)(k+u)*BB + b) << 13) + rem;
      HENDb[idx] = f2b(h0);
      h0 = fmaf(__expf(ds[u]*A), h0, he[u]);
    }
  }
}

// ---------------- scan phase C: recomputes dt from DTR rows + wdt (no DXb);
// xp from XPb; BM/CM/DTR rows staged in LDS; full scan with h0, gate, bf16 out.
__global__ __launch_bounds__(256) void scanC_k(const u16* __restrict__ XPb,
    const float* __restrict__ DTR, const u16* __restrict__ XZb,
    const float* __restrict__ BM, const float* __restrict__ CM,
    const float* __restrict__ Wdt, const float* __restrict__ bdt,
    const float* __restrict__ Alog, const float* __restrict__ Dp,
    const u16* __restrict__ H0b, u16* __restrict__ YGb)
{
  __shared__ float ROWa[SEG_L*16];      // BM rows
  __shared__ float ROWc[SEG_L*16];      // CM rows
  __shared__ float ROWd[SEG_L*16];      // DTR rows
  const int tid = threadIdx.x;
  const int seg = blockIdx.x, b = blockIdx.y, half = blockIdx.z;
  const int c = half*256 + tid;
  const int t0 = seg*SEG_L;
  const size_t base = (size_t)t0*BB + b;
  for (int idx = tid; idx < SEG_L*16; idx += 256) {
    int t = idx >> 4, j = idx & 15;
    size_t off = (base + (size_t)t*BB)*16 + j;
    ROWa[idx] = BM[off];
    ROWc[idx] = CM[off];
    ROWd[idx] = DTR[off];
  }
  float As0 = -__expf(Alog[c*16]);
  bool uni = true;
  #pragma unroll
  for (int s = 1; s < 16; ++s) {
    float Av = -__expf(Alog[c*16+s]);
    uni = uni && (fabsf(Av - As0*(float)(s+1)) <= 1e-4f*(float)(s+1));
  }
  float wdt[16];
  #pragma unroll
  for (int r = 0; r < 16; ++r) wdt[r] = Wdt[r*DINNER + c];
  const float bd = bdt[c];
  float h[16];
  const u16* hp = &H0b[(((size_t)seg*BB + b)*DINNER + c)*16];
  #pragma unroll
  for (int q = 0; q < 4; ++q) {
    ushort4 hv = *(const ushort4*)&hp[q*4];
    h[q*4+0]=b2f(hv.x); h[q*4+1]=b2f(hv.y); h[q*4+2]=b2f(hv.z); h[q*4+3]=b2f(hv.w);
  }
  const float Dv = Dp[c];
  const u16* xpp = XPb + base*DINNER + c;
  const u16* zp  = XZb + base*1024 + DINNER + c;
  u16*       ygp = YGb + base*DINNER + c;
  __syncthreads();
  float xp = b2f(xpp[0]);
  float zg = b2f(zp[0]);
  for (int t = 0; t < SEG_L; ++t) {
    float xpn = 0.f, zgn = 0.f;
    if (t+1 < SEG_L) {
      xpn = b2f(xpp[(size_t)(t+1)*BB*DINNER]);
      zgn = b2f(zp[(size_t)(t+1)*BB*1024]);
    }
    float dsum = bd;
    #pragma unroll
    for (int r = 0; r < 16; ++r) dsum = fmaf(ROWd[t*16+r], wdt[r], dsum);
    float dt = (dsum > 20.f) ? dsum : __logf(1.f + __expf(dsum));
    float dtx = dt * xp;
    float dA[16];
    compute_dA(dt, As0, uni, Alog, c, dA);
    float4 ra0 = *(const float4*)&ROWa[t*16 + 0];
    float4 ra1 = *(const float4*)&ROWa[t*16 + 4];
    float4 ra2 = *(const float4*)&ROWa[t*16 + 8];
    float4 ra3 = *(const float4*)&ROWa[t*16 + 12];
    float4 rc0 = *(const float4*)&ROWc[t*16 + 0];
    float4 rc1 = *(const float4*)&ROWc[t*16 + 4];
    float4 rc2 = *(const float4*)&ROWc[t*16 + 8];
    float4 rc3 = *(const float4*)&ROWc[t*16 + 12];
    float y0 = 0.f, y1 = 0.f, y2 = 0.f, y3 = 0.f;
    h[0]  = fmaf(dA[0],  h[0],  dtx*ra0.x); y0 = fmaf(h[0],  rc0.x, y0);
    h[1]  = fmaf(dA[1],  h[1],  dtx*ra0.y); y1 = fmaf(h[1],  rc0.y, y1);
    h[2]  = fmaf(dA[2],  h[2],  dtx*ra0.z); y2 = fmaf(h[2],  rc0.z, y2);
    h[3]  = fmaf(dA[3],  h[3],  dtx*ra0.w); y3 = fmaf(h[3],  rc0.w, y3);
    h[4]  = fmaf(dA[4],  h[4],  dtx*ra1.x); y0 = fmaf(h[4],  rc1.x, y0);
    h[5]  = fmaf(dA[5],  h[5],  dtx*ra1.y); y1 = fmaf(h[5],  rc1.y, y1);
    h[6]  = fmaf(dA[6],  h[6],  dtx*ra1.z); y2 = fmaf(h[6],  rc1.z, y2);
    h[7]  = fmaf(dA[7],  h[7],  dtx*ra1.w); y3 = fmaf(h[7],  rc1.w, y3);
    h[8]  = fmaf(dA[8],  h[8],  dtx*ra2.x); y0 = fmaf(h[8],  rc2.x, y0);
    h[9]  = fmaf(dA[9],  h[9],  dtx*ra2.y); y1 = fmaf(h[9],  rc2.y, y1);
    h[10] = fmaf(dA[10], h[10], dtx*ra2.z); y2 = fmaf(h[10], rc2.z, y2);
    h[11] = fmaf(dA[11], h[11], dtx*ra2.w); y3 = fmaf(h[11], rc2.w, y3);
    h[12] = fmaf(dA[12], h[12], dtx*ra3.x); y0 = fmaf(h[12], rc3.x, y0);
    h[13] = fmaf(dA[13], h[13], dtx*ra3.y); y1 = fmaf(h[13], rc3.y, y1);
    h[14] = fmaf(dA[14], h[14], dtx*ra3.z); y2 = fmaf(h[14], rc3.z, y2);
    h[15] = fmaf(dA[15], h[15], dtx*ra3.w); y3 = fmaf(h[15], rc3.w, y3);
    float y = (y0+y1) + (y2+y3);
    ygp[(size_t)t*BB*DINNER] = f2b((y + xp*Dv) * siluf(zg));
    xp = xpn; zg = zgn;
  }
}

// ---------------- fused out-proj (BK=64) + residual + action head + log-prob
__global__ __launch_bounds__(256) void outhead_k(const u16* __restrict__ YGb,
    const u16* __restrict__ WTo, const u16* __restrict__ Xb,
    const u16* __restrict__ WhT, const float* __restrict__ bh,
    const float* __restrict__ lstd, const float* __restrict__ a,
    float* __restrict__ out)
{
  __shared__ u16 SH[(64+256)*72];
  u16* As = SH;
  u16* Bs = SH + 64*72;
  const int tid = threadIdx.x;
  const int wave = tid >> 6, lane = tid & 63;
  const int quad = lane >> 4, l16 = lane & 15;
  const int m0 = blockIdx.x*64;
  const int n0 = wave*64;
  const int srow = tid >> 3, sch = (tid & 7)*8;
  floatx4 acc[4][4];
  #pragma unroll
  for (int r = 0; r < 4; ++r)
    #pragma unroll
    for (int c = 0; c < 4; ++c) acc[r][c] = (floatx4){0.f,0.f,0.f,0.f};

  for (int k0 = 0; k0 < DINNER; k0 += 64) {
    #pragma unroll
    for (int p = 0; p < 2; ++p) {
      int row = srow + p*32;
      *(uint4*)&As[row*72 + sch] = *(const uint4*)&YGb[(size_t)(m0+row)*DINNER + k0 + sch];
    }
    #pragma unroll
    for (int p = 0; p < 8; ++p) {
      int row = srow + p*32;
      *(uint4*)&Bs[row*72 + sch] = *(const uint4*)&WTo[(size_t)row*DINNER + k0 + sch];
    }
    __syncthreads();
    #pragma unroll
    for (int ks = 0; ks < 2; ++ks) {
      bf16x8 af[4], bf[4];
      #pragma unroll
      for (int r = 0; r < 4; ++r)
        af[r] = *(const bf16x8*)&As[(r*16 + l16)*72 + ks*32 + quad*8];
      #pragma unroll
      for (int c = 0; c < 4; ++c)
        bf[c] = *(const bf16x8*)&Bs[(n0 + c*16 + l16)*72 + ks*32 + quad*8];
      #pragma unroll
      for (int r = 0; r < 4; ++r)
        #pragma unroll
        for (int c = 0; c < 4; ++c)
          acc[r][c] = __builtin_amdgcn_mfma_f32_16x16x32_bf16(af[r], bf[c], acc[r][c], 0, 0, 0);
    }
    __syncthreads();
  }
  u16* Xs = SH;                         // [64][264]
  #pragma unroll
  for (int p = 0; p < 8; ++p) {
    int row = p*8 + (tid >> 5);
    int col = (tid & 31)*8;
    *(uint4*)&Xs[row*264 + col] = *(const uint4*)&Xb[(size_t)(m0+row)*256 + col];
  }
  __syncthreads();
  #pragma unroll
  for (int c = 0; c < 4; ++c) {
    int n = n0 + c*16 + l16;
    #pragma unroll
    for (int r = 0; r < 4; ++r) {
      #pragma unroll
      for (int reg = 0; reg < 4; ++reg) {
        int ml = r*16 + quad*4 + reg;
        Xs[ml*264 + n] = f2b(acc[r][c][reg] + b2f(Xs[ml*264 + n]));
      }
    }
  }
  __syncthreads();
  floatx4 mu[2];
  mu[0] = (floatx4){0.f,0.f,0.f,0.f};
  mu[1] = (floatx4){0.f,0.f,0.f,0.f};
  #pragma unroll
  for (int k0 = 0; k0 < DMODEL; k0 += 32) {
    bf16x8 axf = *(const bf16x8*)&Xs[(wave*16 + l16)*264 + k0 + quad*8];
    #pragma unroll
    for (int nt = 0; nt < 2; ++nt) {
      bf16x8 bwf = *(const bf16x8*)(WhT + (size_t)(nt*16 + l16)*DMODEL + k0 + quad*8);
      mu[nt] = __builtin_amdgcn_mfma_f32_16x16x32_bf16(axf, bwf, mu[nt], 0, 0, 0);
    }
  }
  float ls0 = lstd[l16],      els0 = __expf(-ls0), bh0 = bh[l16];
  float ls1 = lstd[16 + l16], els1 = __expf(-ls1), bh1 = bh[16 + l16];
  #pragma unroll
  for (int reg = 0; reg < 4; ++reg) {
    int tok = m0 + wave*16 + quad*4 + reg;
    float m0v = mu[0][reg] + bh0;
    float m1v = mu[1][reg] + bh1;
    float z0 = (a[(size_t)tok*32 + l16]      - m0v) * els0;
    float z1 = (a[(size_t)tok*32 + 16 + l16] - m1v) * els1;
    float t = (-0.5f*z0*z0 - ls0) + (-0.5f*z1*z1 - ls1) - 2.f*0.91893853320467274f;
    t += __shfl_xor(t, 1);
    t += __shfl_xor(t, 2);
    t += __shfl_xor(t, 4);
    t += __shfl_xor(t, 8);
    if (l16 == 0) out[tok] = t;
  }
}

extern "C" void kernel_launch(void* const* d_in, const int* in_sizes, int n_in,
                              void* d_out, int out_size, void* d_ws, size_t ws_size,
                              hipStream_t stream)
{
  const float* s    = (const float*)d_in[0];
  const float* a    = (const float*)d_in[1];
  const float* Wemb = (const float*)d_in[2];
  const float* bemb = (const float*)d_in[3];
  const float* nw   = (const float*)d_in[4];
  const float* Win  = (const float*)d_in[5];
  const float* cw   = (const float*)d_in[6];
  const float* cb   = (const float*)d_in[7];
  const float* Wx   = (const float*)d_in[8];
  const float* Wdt  = (const float*)d_in[9];
  const float* bdt  = (const float*)d_in[10];
  const float* Alog = (const float*)d_in[11];
  const float* Dp   = (const float*)d_in[12];
  const float* Wout = (const float*)d_in[13];
  const float* Wh   = (const float*)d_in[14];
  const float* bh   = (const float*)d_in[15];
  const float* lstd = (const float*)d_in[16];

  // -------- workspace layout (~140 MB)
  u16*   Xb   = (u16*)d_ws;                         // NTOK*256 bf16 (emb resid)
  u16*   XZb  = Xb  + (size_t)NTOK*DMODEL;          // NTOK*1024 bf16 [xp|z]
  u16*   XNb  = XZb + (size_t)NTOK*1024;            // NTOK*256 bf16
  u16*   YGb  = XNb + (size_t)NTOK*DMODEL;          // NTOK*512 bf16
  u16*   WTe  = YGb + (size_t)NTOK*DINNER;          // 256*128
  u16*   WTi  = WTe + 256*128;                      // 1024*256
  u16*   WTo  = WTi + 1024*256;                     // 256*512
  u16*   WxT  = WTo + 256*512;                      // 48*512
  u16*   WhT  = WxT + 48*512;                       // 32*256
  u16*   HENDb= WhT + 32*256;                       // NSEG*8*512*16 bf16 (SEG_N used)
  u16*   XPb  = HENDb + (size_t)NSEG*BB*DINNER*16;  // NTOK*512 bf16 (conv+silu xp)
  unsigned* DXb = (unsigned*)(XPb + (size_t)NTOK*DINNER); // unused now
  float* BM   = (float*)(DXb + (size_t)NTOK*DINNER);// NTOK*16 fp32
  float* CM   = BM + (size_t)NTOK*16;               // NTOK*16 fp32
  float* DTR  = CM + (size_t)NTOK*16;               // NTOK*16 fp32
  float* DTS  = DTR + (size_t)NTOK*16;              // NSEG*8*512 fp32
  float* out  = (float*)d_out;

  prep_k        <<<352,         256, 0, stream>>>(Wemb, Win, Wout, Wx, Wh,
                                                  WTe, WTi, WTo, WxT, WhT);
  embnorm_k     <<<256,         256, 0, stream>>>(s, WTe, bemb, nw, Xb, XNb);
  gemm_mfma<256><<<dim3(128,8), 256, 0, stream>>>(XNb, WTi, XZb, 1024);
  xdblBC_k      <<<256,         256, 0, stream>>>(XZb, cw, cb, WxT, BM, CM, DTR, XPb);
  scanA_k       <<<dim3(SEG_N,BB,2), 256, 0, stream>>>(DTR, XPb, BM, Wdt, bdt,
                                                       Alog, HENDb, DTS);
  stitch_k      <<<256,         256, 0, stream>>>(HENDb, DTS, Alog);
  scanC_k       <<<dim3(SEG_N,BB,2), 256, 0, stream>>>(XPb, DTR, XZb, BM, CM,
                                                       Wdt, bdt, Alog, Dp, HENDb, YGb);
  outhead_k     <<<256,         256, 0, stream>>>(YGb, WTo, Xb, WhT, bh, lstd, a, out);
}

// Round 11
// 228.596 us; speedup vs baseline: 1.0081x; 1.0081x over previous
//
#include <hip/hip_runtime.h>

typedef unsigned short u16;
typedef short bf16x8 __attribute__((ext_vector_type(8)));   // 8 bf16 = 4 VGPR
typedef float floatx4 __attribute__((ext_vector_type(4)));

#define LSEQ 2048
#define BB 8
#define NTOK (LSEQ*BB)        // 16384 tokens, n = l*B + b
#define DMODEL 256
#define DINNER 512
#define NSEG 128              // workspace sizing
#define SEG_N 128             // segments used by scan/stitch (32 waves/CU)
#define SEG_L 16              // LSEQ / SEG_N

__device__ __forceinline__ float siluf(float x){ return x / (1.f + __expf(-x)); }
__device__ __forceinline__ float b2f(u16 x){ return __uint_as_float(((unsigned)x) << 16); }
__device__ __forceinline__ u16 f2b(float f){
  unsigned u = __float_as_uint(f);
  unsigned r = (u + 0x7fffu + ((u >> 16) & 1u)) >> 16;
  return (u16)r;
}

// async global->LDS, 16B per lane; LDS dest is wave-uniform base + lane*16B.
__device__ __forceinline__ void gload16(const u16* g, u16* l) {
  __builtin_amdgcn_global_load_lds(
      (const __attribute__((address_space(1))) unsigned int*)g,
      (__attribute__((address_space(3))) unsigned int*)l, 16, 0, 0);
}

// dA powers: uni fast path (A_s = (s+1)*A_0) needs only As0; fallback re-reads Alog.
__device__ __forceinline__ void compute_dA(float dt, float As0, bool uni,
    const float* __restrict__ Alog, int c, float* dA)
{
  if (uni) {
    float p = __expf(dt*As0);
    float p2 = p*p, p4 = p2*p2, p8 = p4*p4;
    dA[0]=p;      dA[1]=p2;     dA[2]=p2*p;   dA[3]=p4;
    dA[4]=p4*p;   dA[5]=p4*p2;  dA[6]=p4*p2*p;dA[7]=p8;
    dA[8]=p8*p;   dA[9]=p8*p2;  dA[10]=p8*p2*p; dA[11]=p8*p4;
    dA[12]=p8*p4*p; dA[13]=p8*p4*p2; dA[14]=p8*p4*p2*p; dA[15]=p8*p8;
  } else {
    #pragma unroll
    for (int s = 0; s < 16; ++s) dA[s] = __expf(dt * (-__expf(Alog[c*16+s])));
  }
}

// ---------------- prep: weight transpose/casts (tiled for the two big ones)
__global__ __launch_bounds__(256) void prep_k(
    const float* __restrict__ Wemb, const float* __restrict__ Win,
    const float* __restrict__ Wout, const float* __restrict__ Wx,
    const float* __restrict__ Wh,
    u16* __restrict__ WTe, u16* __restrict__ WTi, u16* __restrict__ WTo,
    u16* __restrict__ WxT, u16* __restrict__ WhT)
{
  __shared__ u16 T[64*66];
  int g = blockIdx.x, tid = threadIdx.x;
  if (g < 96) {                         // tiled transposes
    const float* src; u16* dst; int n0, k0, srcld, dstld;
    if (g < 64) {                       // WTi[n][k] = Win[k*1024+n], n<1024,k<256
      int tn = g & 15, tk = g >> 4;
      n0 = tn*64; k0 = tk*64; src = Win; dst = WTi; srcld = 1024; dstld = 256;
    } else {                            // WTo[n][k] = Wout[k*256+n], n<256,k<512
      int g2 = g - 64;
      int tn = g2 & 3, tk = g2 >> 2;
      n0 = tn*64; k0 = tk*64; src = Wout; dst = WTo; srcld = 256; dstld = 512;
    }
    int rr = tid >> 6, cc = tid & 63;
    #pragma unroll
    for (int p = 0; p < 16; ++p) {
      int kr = p*4 + rr;
      T[kr*66 + cc] = f2b(src[(size_t)(k0+kr)*srcld + n0 + cc]);
    }
    __syncthreads();
    #pragma unroll
    for (int p = 0; p < 16; ++p) {
      int nr = p*4 + rr;
      dst[(size_t)(n0+nr)*dstld + k0 + cc] = T[cc*66 + nr];
    }
  } else if (g < 224) {                 // WTe[n][k], n<256, k<128
    int idx = (g-96)*256 + tid; int n = idx >> 7, k = idx & 127;
    WTe[idx] = f2b(Wemb[(size_t)k*256 + n]);
  } else if (g < 320) {                 // WxT[48][512]
    int idx = (g-224)*256 + tid; int n = idx >> 9, k = idx & 511;
    WxT[idx] = f2b(Wx[(size_t)k*48 + n]);
  } else {                              // WhT[32][256]
    int idx = (g-320)*256 + tid; int j = idx >> 8, k = idx & 255;
    WhT[idx] = f2b(Wh[(size_t)k*32 + j]);
  }
}

// ---------------- fused emb GEMM + RMSNorm: block = 64 tokens x full N=256.
__global__ __launch_bounds__(256) void embnorm_k(
    const float* __restrict__ s, const u16* __restrict__ WTe,
    const float* __restrict__ bemb, const float* __restrict__ nw,
    u16* __restrict__ Xb, u16* __restrict__ XNb)
{
  __shared__ u16 SH[64*264];
  __shared__ float ssq[64*4];
  __shared__ float rr[64];
  u16* As = SH;
  u16* Bs = SH + 64*40;
  const int tid = threadIdx.x;
  const int wave = tid >> 6, lane = tid & 63;
  const int quad = lane >> 4, l16 = lane & 15;
  const int m0 = blockIdx.x*64;
  const int wn = wave*64;
  const int srow = tid >> 2, sch = (tid & 3)*8;
  floatx4 acc[4][4];
  #pragma unroll
  for (int r = 0; r < 4; ++r)
    #pragma unroll
    for (int c = 0; c < 4; ++c) acc[r][c] = (floatx4){0.f,0.f,0.f,0.f};

  for (int k0 = 0; k0 < 128; k0 += 32) {
    {
      float4 v0 = *(const float4*)&s[(size_t)(m0+srow)*128 + k0 + sch];
      float4 v1 = *(const float4*)&s[(size_t)(m0+srow)*128 + k0 + sch + 4];
      __align__(16) u16 o[8];
      o[0]=f2b(v0.x); o[1]=f2b(v0.y); o[2]=f2b(v0.z); o[3]=f2b(v0.w);
      o[4]=f2b(v1.x); o[5]=f2b(v1.y); o[6]=f2b(v1.z); o[7]=f2b(v1.w);
      *(uint4*)&As[srow*40 + sch] = *(const uint4*)o;
    }
    #pragma unroll
    for (int p = 0; p < 4; ++p) {
      int row = srow + p*64;
      *(uint4*)&Bs[row*40 + sch] = *(const uint4*)&WTe[(size_t)row*128 + k0 + sch];
    }
    __syncthreads();
    bf16x8 af[4], bf[4];
    #pragma unroll
    for (int r = 0; r < 4; ++r) af[r] = *(const bf16x8*)&As[(r*16 + l16)*40 + quad*8];
    #pragma unroll
    for (int c = 0; c < 4; ++c) bf[c] = *(const bf16x8*)&Bs[(wn + c*16 + l16)*40 + quad*8];
    #pragma unroll
    for (int r = 0; r < 4; ++r)
      #pragma unroll
      for (int c = 0; c < 4; ++c)
        acc[r][c] = __builtin_amdgcn_mfma_f32_16x16x32_bf16(af[r], bf[c], acc[r][c], 0, 0, 0);
    __syncthreads();
  }
  u16* Xs = SH;                         // [64][264]
  #pragma unroll
  for (int c = 0; c < 4; ++c) {
    int n = wn + c*16 + l16;
    float bv = bemb[n];
    #pragma unroll
    for (int r = 0; r < 4; ++r)
      #pragma unroll
      for (int reg = 0; reg < 4; ++reg) {
        int ml = r*16 + quad*4 + reg;
        Xs[ml*264 + n] = f2b(acc[r][c][reg] + bv);
      }
  }
  __syncthreads();
  #pragma unroll
  for (int p = 0; p < 8; ++p) {
    int row = p*8 + (tid >> 5);
    int col = (tid & 31)*8;
    *(uint4*)&Xb[(size_t)(m0+row)*256 + col] = *(const uint4*)&Xs[row*264 + col];
  }
  const int tk = tid >> 2, q = tid & 3;
  float ss = 0.f;
  #pragma unroll
  for (int j = 0; j < 8; ++j) {
    uint4 v = *(const uint4*)&Xs[tk*264 + q*64 + j*8];
    const u16* u = (const u16*)&v;
    #pragma unroll
    for (int i = 0; i < 8; ++i) { float x = b2f(u[i]); ss += x*x; }
  }
  ssq[tk*4 + q] = ss;
  __syncthreads();
  if (q == 0)
    rr[tk] = rsqrtf((ssq[tk*4]+ssq[tk*4+1]+ssq[tk*4+2]+ssq[tk*4+3])*(1.f/DMODEL) + 1e-5f);
  __syncthreads();
  float r = rr[tk];
  #pragma unroll
  for (int j = 0; j < 8; ++j) {
    int idx = q*64 + j*8;
    uint4 v = *(const uint4*)&Xs[tk*264 + idx];
    const u16* u = (const u16*)&v;
    float4 w0 = *(const float4*)&nw[idx];
    float4 w1 = *(const float4*)&nw[idx+4];
    __align__(16) u16 o[8];
    o[0]=f2b(b2f(u[0])*r*w0.x); o[1]=f2b(b2f(u[1])*r*w0.y);
    o[2]=f2b(b2f(u[2])*r*w0.z); o[3]=f2b(b2f(u[3])*r*w0.w);
    o[4]=f2b(b2f(u[4])*r*w1.x); o[5]=f2b(b2f(u[5])*r*w1.y);
    o[6]=f2b(b2f(u[6])*r*w1.z); o[7]=f2b(b2f(u[7])*r*w1.w);
    *(uint4*)&XNb[(size_t)(m0+tk)*256 + idx] = *(const uint4*)o;
  }
}

// ---------------- in-proj GEMM, BK=64, global_load_lds staging + XOR-swizzled
// LDS (linear dest, inverse-swizzled source, swizzled ds_read — rule #21).
template<int K>
__global__ __launch_bounds__(256) void gemm_mfma(
    const u16* __restrict__ Ab, const u16* __restrict__ WT,
    u16* __restrict__ Cv, int N)
{
  __shared__ __align__(16) u16 SH[17408];   // staging 2*128*64=16384; Cs 128*136
  u16* As = SH;
  u16* Bs = SH + 128*64;
  const int tid = threadIdx.x;
  const int wave = tid >> 6, lane = tid & 63;
  const int quad = lane >> 4, l16 = lane & 15;
  const int bm0 = blockIdx.x*128, bn0 = blockIdx.y*128;
  const int wm = (wave & 1)*64, wn = (wave >> 1)*64;
  floatx4 acc[4][4];
  #pragma unroll
  for (int r = 0; r < 4; ++r)
    #pragma unroll
    for (int c = 0; c < 4; ++c) acc[r][c] = (floatx4){0.f,0.f,0.f,0.f};

  for (int k0 = 0; k0 < K; k0 += 64) {
    #pragma unroll
    for (int p = 0; p < 4; ++p) {
      int cid = (wave*4 + p)*64 + lane;
      int row = cid >> 3, sch = (cid & 7) ^ (row & 7);
      gload16(&Ab[(size_t)(bm0+row)*K + k0 + sch*8], As + (wave*4+p)*512);
      gload16(&WT[(size_t)(bn0+row)*K + k0 + sch*8], Bs + (wave*4+p)*512);
    }
    __syncthreads();
    #pragma unroll
    for (int ks = 0; ks < 2; ++ks) {
      bf16x8 af[4], bf[4];
      #pragma unroll
      for (int r = 0; r < 4; ++r) {
        int row = wm + r*16 + l16;
        int lch = (ks*4 + quad) ^ (row & 7);
        af[r] = *(const bf16x8*)&As[row*64 + lch*8];
      }
      #pragma unroll
      for (int c = 0; c < 4; ++c) {
        int row = wn + c*16 + l16;
        int lch = (ks*4 + quad) ^ (row & 7);
        bf[c] = *(const bf16x8*)&Bs[row*64 + lch*8];
      }
      #pragma unroll
      for (int r = 0; r < 4; ++r)
        #pragma unroll
        for (int c = 0; c < 4; ++c)
          acc[r][c] = __builtin_amdgcn_mfma_f32_16x16x32_bf16(af[r], bf[c], acc[r][c], 0, 0, 0);
    }
    __syncthreads();
  }
  u16* Cs = SH;                         // [128][136]
  #pragma unroll
  for (int c = 0; c < 4; ++c) {
    int nl = wn + c*16 + l16;
    #pragma unroll
    for (int r = 0; r < 4; ++r)
      #pragma unroll
      for (int reg = 0; reg < 4; ++reg) {
        int ml = wm + r*16 + quad*4 + reg;
        Cs[ml*136 + nl] = f2b(acc[r][c][reg]);
      }
  }
  __syncthreads();
  #pragma unroll
  for (int p = 0; p < 8; ++p) {
    int row = p*16 + (tid >> 4);
    int col = (tid & 15)*8;
    uint4 v = *(const uint4*)&Cs[row*136 + col];
    *(uint4*)&Cv[(size_t)(bm0+row)*N + bn0 + col] = v;
  }
}

// ---------------- x_dbl GEMM1 with fused causal conv+SiLU in the staging phase.
// Persists conv output xp to XPb so the scans never redo the conv.
__global__ __launch_bounds__(256) void xdblBC_k(const u16* __restrict__ XZb,
    const float* __restrict__ cw, const float* __restrict__ cb,
    const u16* __restrict__ WxT,
    float* __restrict__ BM, float* __restrict__ CM, float* __restrict__ DTR,
    u16* __restrict__ XPb)
{
  __shared__ u16 As[64*40];
  __shared__ u16 Ws[48*40];
  __shared__ float CWs[512*4];
  __shared__ float CBs[512];
  const int tid = threadIdx.x;
  const int wave = tid >> 6, lane = tid & 63;
  const int quad = lane >> 4, l16 = lane & 15;
  const int m0 = blockIdx.x*64;
  const int srow = tid >> 2, sch = (tid & 3)*8;
  const int n = m0 + srow;
  for (int e = tid; e < 2048; e += 256) CWs[e] = cw[e];
  for (int e = tid; e < 512;  e += 256) CBs[e] = cb[e];
  floatx4 acc[3];
  #pragma unroll
  for (int j = 0; j < 3; ++j) acc[j] = (floatx4){0.f,0.f,0.f,0.f};
  __syncthreads();
  const bf16x8 z8 = {0,0,0,0,0,0,0,0};
  for (int k0 = 0; k0 < DINNER; k0 += 32) {
    bf16x8 t3 = *(const bf16x8*)&XZb[(size_t)n*1024 + k0 + sch];
    bf16x8 t2 = z8, t1 = z8, t0v = z8;
    if (n >= 8)  t2  = *(const bf16x8*)&XZb[(size_t)(n-8)*1024  + k0 + sch];
    if (n >= 16) t1  = *(const bf16x8*)&XZb[(size_t)(n-16)*1024 + k0 + sch];
    if (n >= 24) t0v = *(const bf16x8*)&XZb[(size_t)(n-24)*1024 + k0 + sch];
    __align__(16) u16 outa[8];
    #pragma unroll
    for (int j = 0; j < 8; ++j) {
      int c = k0 + sch + j;
      float4 wv = *(const float4*)&CWs[c*4];
      float xc = CBs[c] + wv.x*b2f((u16)t0v[j]) + wv.y*b2f((u16)t1[j])
               + wv.z*b2f((u16)t2[j]) + wv.w*b2f((u16)t3[j]);
      outa[j] = f2b(siluf(xc));
    }
    *(uint4*)&As[srow*40 + sch] = *(const uint4*)outa;
    *(uint4*)&XPb[(size_t)n*DINNER + k0 + sch] = *(const uint4*)outa;
    if (tid < 192) {
      int wr = tid >> 2;
      *(uint4*)&Ws[wr*40 + sch] = *(const uint4*)&WxT[(size_t)wr*512 + k0 + sch];
    }
    __syncthreads();
    bf16x8 af = *(const bf16x8*)&As[(wave*16 + l16)*40 + quad*8];
    #pragma unroll
    for (int j = 0; j < 3; ++j) {
      bf16x8 bf = *(const bf16x8*)&Ws[(j*16 + l16)*40 + quad*8];
      acc[j] = __builtin_amdgcn_mfma_f32_16x16x32_bf16(af, bf, acc[j], 0, 0, 0);
    }
    __syncthreads();
  }
  const int tok0 = m0 + wave*16;
  #pragma unroll
  for (int reg = 0; reg < 4; ++reg) {
    size_t t = (size_t)(tok0 + quad*4 + reg);
    BM[t*16 + l16]  = acc[1][reg];
    CM[t*16 + l16]  = acc[2][reg];
    DTR[t*16 + l16] = acc[0][reg];
  }
}

// ---------------- scan phase A: dt projection inline, xp from XPb (prefetched).
// BM/DTR rows staged in LDS. Stores h_end, sum(dt), packed {dt,xp}.
__global__ __launch_bounds__(256) void scanA_k(const float* __restrict__ DTR,
    const u16* __restrict__ XPb, const float* __restrict__ BM,
    const float* __restrict__ Wdt, const float* __restrict__ bdt,
    const float* __restrict__ Alog, u16* __restrict__ HENDb,
    float* __restrict__ DTS, unsigned* __restrict__ DXb)
{
  __shared__ float ROWa[SEG_L*16];      // BM rows
  __shared__ float ROWb[SEG_L*16];      // DTR rows
  const int tid = threadIdx.x;
  const int seg = blockIdx.x, b = blockIdx.y, half = blockIdx.z;
  const int c = half*256 + tid;
  const int t0 = seg*SEG_L;
  const size_t base = (size_t)t0*BB + b;
  for (int idx = tid; idx < SEG_L*16; idx += 256) {
    int t = idx >> 4, j = idx & 15;
    size_t off = (base + (size_t)t*BB)*16 + j;
    ROWa[idx] = BM[off];
    ROWb[idx] = DTR[off];
  }
  float As0 = -__expf(Alog[c*16]);
  bool uni = true;
  #pragma unroll
  for (int s = 1; s < 16; ++s) {
    float Av = -__expf(Alog[c*16+s]);
    uni = uni && (fabsf(Av - As0*(float)(s+1)) <= 1e-4f*(float)(s+1));
  }
  float wdt[16];
  #pragma unroll
  for (int r = 0; r < 16; ++r) wdt[r] = Wdt[r*DINNER + c];
  const float bd = bdt[c];
  float h[16];
  #pragma unroll
  for (int s = 0; s < 16; ++s) h[s] = 0.f;
  float dts = 0.f;
  const u16* xpp = XPb + base*DINNER + c;
  __syncthreads();
  float xp = b2f(xpp[0]);
  for (int t = 0; t < SEG_L; ++t) {
    float xpn = (t+1 < SEG_L) ? b2f(xpp[(size_t)(t+1)*BB*DINNER]) : 0.f;
    float dsum = bd;
    #pragma unroll
    for (int r = 0; r < 16; ++r) dsum = fmaf(ROWb[t*16+r], wdt[r], dsum);
    float dt = (dsum > 20.f) ? dsum : __logf(1.f + __expf(dsum));
    dts += dt;
    DXb[(((size_t)(t0+t)*BB + b)*DINNER + c)] = ((unsigned)f2b(xp) << 16) | f2b(dt);
    float dtx = dt * xp;
    float dA[16];
    compute_dA(dt, As0, uni, Alog, c, dA);
    float4 r0 = *(const float4*)&ROWa[t*16 + 0];
    float4 r1 = *(const float4*)&ROWa[t*16 + 4];
    float4 r2 = *(const float4*)&ROWa[t*16 + 8];
    float4 r3 = *(const float4*)&ROWa[t*16 + 12];
    h[0]  = fmaf(dA[0],  h[0],  dtx*r0.x);
    h[1]  = fmaf(dA[1],  h[1],  dtx*r0.y);
    h[2]  = fmaf(dA[2],  h[2],  dtx*r0.z);
    h[3]  = fmaf(dA[3],  h[3],  dtx*r0.w);
    h[4]  = fmaf(dA[4],  h[4],  dtx*r1.x);
    h[5]  = fmaf(dA[5],  h[5],  dtx*r1.y);
    h[6]  = fmaf(dA[6],  h[6],  dtx*r1.z);
    h[7]  = fmaf(dA[7],  h[7],  dtx*r1.w);
    h[8]  = fmaf(dA[8],  h[8],  dtx*r2.x);
    h[9]  = fmaf(dA[9],  h[9],  dtx*r2.y);
    h[10] = fmaf(dA[10], h[10], dtx*r2.z);
    h[11] = fmaf(dA[11], h[11], dtx*r2.w);
    h[12] = fmaf(dA[12], h[12], dtx*r3.x);
    h[13] = fmaf(dA[13], h[13], dtx*r3.y);
    h[14] = fmaf(dA[14], h[14], dtx*r3.z);
    h[15] = fmaf(dA[15], h[15], dtx*r3.w);
    xp = xpn;
  }
  u16* hp = &HENDb[(((size_t)seg*BB + b)*DINNER + c)*16];
  #pragma unroll
  for (int q = 0; q < 2; ++q) {
    ushort4 v0, v1;
    v0.x = f2b(h[q*8+0]); v0.y = f2b(h[q*8+1]); v0.z = f2b(h[q*8+2]); v0.w = f2b(h[q*8+3]);
    v1.x = f2b(h[q*8+4]); v1.y = f2b(h[q*8+5]); v1.z = f2b(h[q*8+6]); v1.w = f2b(h[q*8+7]);
    *(ushort4*)&hp[q*8]     = v0;
    *(ushort4*)&hp[q*8 + 4] = v1;
  }
  DTS[((size_t)seg*BB + b)*DINNER + c] = dts;
}

// ---------------- stitch: sequential over SEG_N segments, in-place HENDb -> h0.
// Unroll-by-4 with batched prefetch: one load-stall per 4 iterations.
__global__ __launch_bounds__(256) void stitch_k(u16* __restrict__ HENDb,
    const float* __restrict__ DTS, const float* __restrict__ Alog)
{
  int g = blockIdx.x*256 + threadIdx.x;
  int b = g >> 13;
  int rem = g & 8191;          // c*16+s
  int cidx = rem >> 4;
  float A = -__expf(Alog[rem]);
  float h0 = 0.f;
  for (int k = 0; k < SEG_N; k += 4) {
    float he[4], ds[4];
    #pragma unroll
    for (int u = 0; u < 4; ++u) {
      size_t idx = (((size_t)(k+u)*BB + b) << 13) + rem;
      he[u] = b2f(HENDb[idx]);
      ds[u] = DTS[((size_t)(k+u)*BB + b)*DINNER + cidx];
    }
    #pragma unroll
    for (int u = 0; u < 4; ++u) {
      size_t idx = (((size_t)(k+u)*BB + b) << 13) + rem;
      HENDb[idx] = f2b(h0);
      h0 = fmaf(__expf(ds[u]*A), h0, he[u]);
    }
  }
}

// ---------------- scan phase C: packed {dt,xp}; BM/CM rows staged once per
// block in LDS; full scan with h0, gate, bf16 out. Prefetch dx/zg one step.
__global__ __launch_bounds__(256) void scanC_k(const unsigned* __restrict__ DXb,
    const u16* __restrict__ XZb, const float* __restrict__ BM, const float* __restrict__ CM,
    const float* __restrict__ Alog, const float* __restrict__ Dp,
    const u16* __restrict__ H0b, u16* __restrict__ YGb)
{
  __shared__ float ROWa[SEG_L*16];      // BM rows
  __shared__ float ROWc[SEG_L*16];      // CM rows
  const int tid = threadIdx.x;
  const int seg = blockIdx.x, b = blockIdx.y, half = blockIdx.z;
  const int c = half*256 + tid;
  const int t0 = seg*SEG_L;
  const size_t base = (size_t)t0*BB + b;
  for (int idx = tid; idx < SEG_L*16; idx += 256) {
    int t = idx >> 4, j = idx & 15;
    size_t off = (base + (size_t)t*BB)*16 + j;
    ROWa[idx] = BM[off];
    ROWc[idx] = CM[off];
  }
  float As0 = -__expf(Alog[c*16]);
  bool uni = true;
  #pragma unroll
  for (int s = 1; s < 16; ++s) {
    float Av = -__expf(Alog[c*16+s]);
    uni = uni && (fabsf(Av - As0*(float)(s+1)) <= 1e-4f*(float)(s+1));
  }
  float h[16];
  const u16* hp = &H0b[(((size_t)seg*BB + b)*DINNER + c)*16];
  #pragma unroll
  for (int q = 0; q < 4; ++q) {
    ushort4 hv = *(const ushort4*)&hp[q*4];
    h[q*4+0]=b2f(hv.x); h[q*4+1]=b2f(hv.y); h[q*4+2]=b2f(hv.z); h[q*4+3]=b2f(hv.w);
  }
  const float Dv = Dp[c];
  const unsigned* dxp = DXb + base*DINNER + c;
  const u16* zp  = XZb + base*1024 + DINNER + c;
  u16*       ygp = YGb + base*DINNER + c;
  __syncthreads();
  unsigned dx = dxp[0];
  float zg = b2f(zp[0]);
  for (int t = 0; t < SEG_L; ++t) {
    unsigned dxn = 0; float zgn = 0.f;
    if (t+1 < SEG_L) {
      dxn = dxp[(size_t)(t+1)*BB*DINNER];
      zgn = b2f(zp[(size_t)(t+1)*BB*1024]);
    }
    float dt = __uint_as_float(dx << 16);
    float xp = __uint_as_float(dx & 0xffff0000u);
    float dtx = dt * xp;
    float dA[16];
    compute_dA(dt, As0, uni, Alog, c, dA);
    float4 ra0 = *(const float4*)&ROWa[t*16 + 0];
    float4 ra1 = *(const float4*)&ROWa[t*16 + 4];
    float4 ra2 = *(const float4*)&ROWa[t*16 + 8];
    float4 ra3 = *(const float4*)&ROWa[t*16 + 12];
    float4 rc0 = *(const float4*)&ROWc[t*16 + 0];
    float4 rc1 = *(const float4*)&ROWc[t*16 + 4];
    float4 rc2 = *(const float4*)&ROWc[t*16 + 8];
    float4 rc3 = *(const float4*)&ROWc[t*16 + 12];
    float y0 = 0.f, y1 = 0.f, y2 = 0.f, y3 = 0.f;
    h[0]  = fmaf(dA[0],  h[0],  dtx*ra0.x); y0 = fmaf(h[0],  rc0.x, y0);
    h[1]  = fmaf(dA[1],  h[1],  dtx*ra0.y); y1 = fmaf(h[1],  rc0.y, y1);
    h[2]  = fmaf(dA[2],  h[2],  dtx*ra0.z); y2 = fmaf(h[2],  rc0.z, y2);
    h[3]  = fmaf(dA[3],  h[3],  dtx*ra0.w); y3 = fmaf(h[3],  rc0.w, y3);
    h[4]  = fmaf(dA[4],  h[4],  dtx*ra1.x); y0 = fmaf(h[4],  rc1.x, y0);
    h[5]  = fmaf(dA[5],  h[5],  dtx*ra1.y); y1 = fmaf(h[5],  rc1.y, y1);
    h[6]  = fmaf(dA[6],  h[6],  dtx*ra1.z); y2 = fmaf(h[6],  rc1.z, y2);
    h[7]  = fmaf(dA[7],  h[7],  dtx*ra1.w); y3 = fmaf(h[7],  rc1.w, y3);
    h[8]  = fmaf(dA[8],  h[8],  dtx*ra2.x); y0 = fmaf(h[8],  rc2.x, y0);
    h[9]  = fmaf(dA[9],  h[9],  dtx*ra2.y); y1 = fmaf(h[9],  rc2.y, y1);
    h[10] = fmaf(dA[10], h[10], dtx*ra2.z); y2 = fmaf(h[10], rc2.z, y2);
    h[11] = fmaf(dA[11], h[11], dtx*ra2.w); y3 = fmaf(h[11], rc2.w, y3);
    h[12] = fmaf(dA[12], h[12], dtx*ra3.x); y0 = fmaf(h[12], rc3.x, y0);
    h[13] = fmaf(dA[13], h[13], dtx*ra3.y); y1 = fmaf(h[13], rc3.y, y1);
    h[14] = fmaf(dA[14], h[14], dtx*ra3.z); y2 = fmaf(h[14], rc3.z, y2);
    h[15] = fmaf(dA[15], h[15], dtx*ra3.w); y3 = fmaf(h[15], rc3.w, y3);
    float y = (y0+y1) + (y2+y3);
    ygp[(size_t)t*BB*DINNER] = f2b((y + xp*Dv) * siluf(zg));
    dx = dxn; zg = zgn;
  }
}

// ---------------- fused out-proj (BK=64) + residual + action head + log-prob
__global__ __launch_bounds__(256) void outhead_k(const u16* __restrict__ YGb,
    const u16* __restrict__ WTo, const u16* __restrict__ Xb,
    const u16* __restrict__ WhT, const float* __restrict__ bh,
    const float* __restrict__ lstd, const float* __restrict__ a,
    float* __restrict__ out)
{
  __shared__ u16 SH[(64+256)*72];
  u16* As = SH;
  u16* Bs = SH + 64*72;
  const int tid = threadIdx.x;
  const int wave = tid >> 6, lane = tid & 63;
  const int quad = lane >> 4, l16 = lane & 15;
  const int m0 = blockIdx.x*64;
  const int n0 = wave*64;
  const int srow = tid >> 3, sch = (tid & 7)*8;
  floatx4 acc[4][4];
  #pragma unroll
  for (int r = 0; r < 4; ++r)
    #pragma unroll
    for (int c = 0; c < 4; ++c) acc[r][c] = (floatx4){0.f,0.f,0.f,0.f};

  for (int k0 = 0; k0 < DINNER; k0 += 64) {
    #pragma unroll
    for (int p = 0; p < 2; ++p) {
      int row = srow + p*32;
      *(uint4*)&As[row*72 + sch] = *(const uint4*)&YGb[(size_t)(m0+row)*DINNER + k0 + sch];
    }
    #pragma unroll
    for (int p = 0; p < 8; ++p) {
      int row = srow + p*32;
      *(uint4*)&Bs[row*72 + sch] = *(const uint4*)&WTo[(size_t)row*DINNER + k0 + sch];
    }
    __syncthreads();
    #pragma unroll
    for (int ks = 0; ks < 2; ++ks) {
      bf16x8 af[4], bf[4];
      #pragma unroll
      for (int r = 0; r < 4; ++r)
        af[r] = *(const bf16x8*)&As[(r*16 + l16)*72 + ks*32 + quad*8];
      #pragma unroll
      for (int c = 0; c < 4; ++c)
        bf[c] = *(const bf16x8*)&Bs[(n0 + c*16 + l16)*72 + ks*32 + quad*8];
      #pragma unroll
      for (int r = 0; r < 4; ++r)
        #pragma unroll
        for (int c = 0; c < 4; ++c)
          acc[r][c] = __builtin_amdgcn_mfma_f32_16x16x32_bf16(af[r], bf[c], acc[r][c], 0, 0, 0);
    }
    __syncthreads();
  }
  u16* Xs = SH;                         // [64][264]
  #pragma unroll
  for (int p = 0; p < 8; ++p) {
    int row = p*8 + (tid >> 5);
    int col = (tid & 31)*8;
    *(uint4*)&Xs[row*264 + col] = *(const uint4*)&Xb[(size_t)(m0+row)*256 + col];
  }
  __syncthreads();
  #pragma unroll
  for (int c = 0; c < 4; ++c) {
    int n = n0 + c*16 + l16;
    #pragma unroll
    for (int r = 0; r < 4; ++r) {
      #pragma unroll
      for (int reg = 0; reg < 4; ++reg) {
        int ml = r*16 + quad*4 + reg;
        Xs[ml*264 + n] = f2b(acc[r][c][reg] + b2f(Xs[ml*264 + n]));
      }
    }
  }
  __syncthreads();
  floatx4 mu[2];
  mu[0] = (floatx4){0.f,0.f,0.f,0.f};
  mu[1] = (floatx4){0.f,0.f,0.f,0.f};
  #pragma unroll
  for (int k0 = 0; k0 < DMODEL; k0 += 32) {
    bf16x8 axf = *(const bf16x8*)&Xs[(wave*16 + l16)*264 + k0 + quad*8];
    #pragma unroll
    for (int nt = 0; nt < 2; ++nt) {
      bf16x8 bwf = *(const bf16x8*)(WhT + (size_t)(nt*16 + l16)*DMODEL + k0 + quad*8);
      mu[nt] = __builtin_amdgcn_mfma_f32_16x16x32_bf16(axf, bwf, mu[nt], 0, 0, 0);
    }
  }
  float ls0 = lstd[l16],      els0 = __expf(-ls0), bh0 = bh[l16];
  float ls1 = lstd[16 + l16], els1 = __expf(-ls1), bh1 = bh[16 + l16];
  #pragma unroll
  for (int reg = 0; reg < 4; ++reg) {
    int tok = m0 + wave*16 + quad*4 + reg;
    float m0v = mu[0][reg] + bh0;
    float m1v = mu[1][reg] + bh1;
    float z0 = (a[(size_t)tok*32 + l16]      - m0v) * els0;
    float z1 = (a[(size_t)tok*32 + 16 + l16] - m1v) * els1;
    float t = (-0.5f*z0*z0 - ls0) + (-0.5f*z1*z1 - ls1) - 2.f*0.91893853320467274f;
    t += __shfl_xor(t, 1);
    t += __shfl_xor(t, 2);
    t += __shfl_xor(t, 4);
    t += __shfl_xor(t, 8);
    if (l16 == 0) out[tok] = t;
  }
}

extern "C" void kernel_launch(void* const* d_in, const int* in_sizes, int n_in,
                              void* d_out, int out_size, void* d_ws, size_t ws_size,
                              hipStream_t stream)
{
  const float* s    = (const float*)d_in[0];
  const float* a    = (const float*)d_in[1];
  const float* Wemb = (const float*)d_in[2];
  const float* bemb = (const float*)d_in[3];
  const float* nw   = (const float*)d_in[4];
  const float* Win  = (const float*)d_in[5];
  const float* cw   = (const float*)d_in[6];
  const float* cb   = (const float*)d_in[7];
  const float* Wx   = (const float*)d_in[8];
  const float* Wdt  = (const float*)d_in[9];
  const float* bdt  = (const float*)d_in[10];
  const float* Alog = (const float*)d_in[11];
  const float* Dp   = (const float*)d_in[12];
  const float* Wout = (const float*)d_in[13];
  const float* Wh   = (const float*)d_in[14];
  const float* bh   = (const float*)d_in[15];
  const float* lstd = (const float*)d_in[16];

  // -------- workspace layout (~140 MB)
  u16*   Xb   = (u16*)d_ws;                         // NTOK*256 bf16 (emb resid)
  u16*   XZb  = Xb  + (size_t)NTOK*DMODEL;          // NTOK*1024 bf16 [xp|z]
  u16*   XNb  = XZb + (size_t)NTOK*1024;            // NTOK*256 bf16
  u16*   YGb  = XNb + (size_t)NTOK*DMODEL;          // NTOK*512 bf16
  u16*   WTe  = YGb + (size_t)NTOK*DINNER;          // 256*128
  u16*   WTi  = WTe + 256*128;                      // 1024*256
  u16*   WTo  = WTi + 1024*256;                     // 256*512
  u16*   WxT  = WTo + 256*512;                      // 48*512
  u16*   WhT  = WxT + 48*512;                       // 32*256
  u16*   HENDb= WhT + 32*256;                       // NSEG*8*512*16 bf16
  u16*   XPb  = HENDb + (size_t)NSEG*BB*DINNER*16;  // NTOK*512 bf16 (conv+silu xp)
  unsigned* DXb = (unsigned*)(XPb + (size_t)NTOK*DINNER); // NTOK*512 u32 {xp,dt}
  float* BM   = (float*)(DXb + (size_t)NTOK*DINNER);// NTOK*16 fp32
  float* CM   = BM + (size_t)NTOK*16;               // NTOK*16 fp32
  float* DTR  = CM + (size_t)NTOK*16;               // NTOK*16 fp32
  float* DTS  = DTR + (size_t)NTOK*16;              // NSEG*8*512 fp32
  float* out  = (float*)d_out;

  prep_k        <<<352,         256, 0, stream>>>(Wemb, Win, Wout, Wx, Wh,
                                                  WTe, WTi, WTo, WxT, WhT);
  embnorm_k     <<<256,         256, 0, stream>>>(s, WTe, bemb, nw, Xb, XNb);
  gemm_mfma<256><<<dim3(128,8), 256, 0, stream>>>(XNb, WTi, XZb, 1024);
  xdblBC_k      <<<256,         256, 0, stream>>>(XZb, cw, cb, WxT, BM, CM, DTR, XPb);
  scanA_k       <<<dim3(SEG_N,BB,2), 256, 0, stream>>>(DTR, XPb, BM, Wdt, bdt,
                                                       Alog, HENDb, DTS, DXb);
  stitch_k      <<<256,         256, 0, stream>>>(HENDb, DTS, Alog);
  scanC_k       <<<dim3(SEG_N,BB,2), 256, 0, stream>>>(DXb, XZb, BM, CM,
                                                       Alog, Dp, HENDb, YGb);
  outhead_k     <<<256,         256, 0, stream>>>(YGb, WTo, Xb, WhT, bh, lstd, a, out);
}

// Round 12
// 223.276 us; speedup vs baseline: 1.0321x; 1.0238x over previous
//
#include <hip/hip_runtime.h>

typedef unsigned short u16;
typedef short bf16x8 __attribute__((ext_vector_type(8)));   // 8 bf16 = 4 VGPR
typedef float floatx4 __attribute__((ext_vector_type(4)));

#define LSEQ 2048
#define BB 8
#define NTOK (LSEQ*BB)        // 16384 tokens, n = l*B + b
#define DMODEL 256
#define DINNER 512
#define NSEG 128              // workspace sizing
#define SEG_N 64              // segments used by scan/stitch (R9 optimum)
#define SEG_L 32              // LSEQ / SEG_N

__device__ __forceinline__ float siluf(float x){ return x / (1.f + __expf(-x)); }
__device__ __forceinline__ float b2f(u16 x){ return __uint_as_float(((unsigned)x) << 16); }
__device__ __forceinline__ u16 f2b(float f){
  unsigned u = __float_as_uint(f);
  unsigned r = (u + 0x7fffu + ((u >> 16) & 1u)) >> 16;
  return (u16)r;
}

// async global->LDS, 16B per lane; LDS dest is wave-uniform base + lane*16B.
__device__ __forceinline__ void gload16(const u16* g, u16* l) {
  __builtin_amdgcn_global_load_lds(
      (const __attribute__((address_space(1))) unsigned int*)g,
      (__attribute__((address_space(3))) unsigned int*)l, 16, 0, 0);
}

// dA powers: uni fast path (A_s = (s+1)*A_0) needs only As0; fallback re-reads Alog.
__device__ __forceinline__ void compute_dA(float dt, float As0, bool uni,
    const float* __restrict__ Alog, int c, float* dA)
{
  if (uni) {
    float p = __expf(dt*As0);
    float p2 = p*p, p4 = p2*p2, p8 = p4*p4;
    dA[0]=p;      dA[1]=p2;     dA[2]=p2*p;   dA[3]=p4;
    dA[4]=p4*p;   dA[5]=p4*p2;  dA[6]=p4*p2*p;dA[7]=p8;
    dA[8]=p8*p;   dA[9]=p8*p2;  dA[10]=p8*p2*p; dA[11]=p8*p4;
    dA[12]=p8*p4*p; dA[13]=p8*p4*p2; dA[14]=p8*p4*p2*p; dA[15]=p8*p8;
  } else {
    #pragma unroll
    for (int s = 0; s < 16; ++s) dA[s] = __expf(dt * (-__expf(Alog[c*16+s])));
  }
}

// ---------------- prep (reduced): only WTe — the sole input of embnorm_k.
__global__ __launch_bounds__(256) void prepWTe_k(
    const float* __restrict__ Wemb, u16* __restrict__ WTe)
{
  int idx = blockIdx.x*256 + threadIdx.x;   // 128 blocks: 256*128 elems
  int n = idx >> 7, k = idx & 127;
  WTe[idx] = f2b(Wemb[(size_t)k*256 + n]);
}

// ---------------- fused emb GEMM + RMSNorm (blocks 0..255) + big weight
// transposes (blocks 256..479 — outputs consumed only by LATER kernels).
__global__ __launch_bounds__(256) void embnorm_k(
    const float* __restrict__ s, const u16* __restrict__ WTe,
    const float* __restrict__ bemb, const float* __restrict__ nw,
    const float* __restrict__ Win, const float* __restrict__ Wout,
    const float* __restrict__ Wx, const float* __restrict__ Wh,
    u16* __restrict__ Xb, u16* __restrict__ XNb,
    u16* __restrict__ WTi, u16* __restrict__ WTo,
    u16* __restrict__ WxT, u16* __restrict__ WhT)
{
  __shared__ u16 SH[64*264];
  __shared__ float ssq[64*4];
  __shared__ float rr[64];
  const int tid = threadIdx.x;

  if (blockIdx.x >= 256) {              // ---- prep tail blocks ----
    int g = blockIdx.x - 256;           // 0..223
    if (g < 96) {                       // tiled transposes via LDS (alias SH)
      u16* T = SH;                      // needs 64*66 u16
      const float* src; u16* dst; int n0, k0, srcld, dstld;
      if (g < 64) {                     // WTi[n][k] = Win[k*1024+n]
        int tn = g & 15, tk = g >> 4;
        n0 = tn*64; k0 = tk*64; src = Win; dst = WTi; srcld = 1024; dstld = 256;
      } else {                          // WTo[n][k] = Wout[k*256+n]
        int g2 = g - 64;
        int tn = g2 & 3, tk = g2 >> 2;
        n0 = tn*64; k0 = tk*64; src = Wout; dst = WTo; srcld = 256; dstld = 512;
      }
      int rr2 = tid >> 6, cc = tid & 63;
      #pragma unroll
      for (int p = 0; p < 16; ++p) {
        int kr = p*4 + rr2;
        T[kr*66 + cc] = f2b(src[(size_t)(k0+kr)*srcld + n0 + cc]);
      }
      __syncthreads();
      #pragma unroll
      for (int p = 0; p < 16; ++p) {
        int nr = p*4 + rr2;
        dst[(size_t)(n0+nr)*dstld + k0 + cc] = T[cc*66 + nr];
      }
    } else if (g < 192) {               // WxT[48][512]
      int idx = (g-96)*256 + tid; int n = idx >> 9, k = idx & 511;
      WxT[idx] = f2b(Wx[(size_t)k*48 + n]);
    } else {                            // WhT[32][256]
      int idx = (g-192)*256 + tid; int j = idx >> 8, k = idx & 255;
      WhT[idx] = f2b(Wh[(size_t)k*32 + j]);
    }
    return;
  }

  // ---- embnorm blocks ----
  u16* As = SH;
  u16* Bs = SH + 64*40;
  const int wave = tid >> 6, lane = tid & 63;
  const int quad = lane >> 4, l16 = lane & 15;
  const int m0 = blockIdx.x*64;
  const int wn = wave*64;
  const int srow = tid >> 2, sch = (tid & 3)*8;
  floatx4 acc[4][4];
  #pragma unroll
  for (int r = 0; r < 4; ++r)
    #pragma unroll
    for (int c = 0; c < 4; ++c) acc[r][c] = (floatx4){0.f,0.f,0.f,0.f};

  for (int k0 = 0; k0 < 128; k0 += 32) {
    {
      float4 v0 = *(const float4*)&s[(size_t)(m0+srow)*128 + k0 + sch];
      float4 v1 = *(const float4*)&s[(size_t)(m0+srow)*128 + k0 + sch + 4];
      __align__(16) u16 o[8];
      o[0]=f2b(v0.x); o[1]=f2b(v0.y); o[2]=f2b(v0.z); o[3]=f2b(v0.w);
      o[4]=f2b(v1.x); o[5]=f2b(v1.y); o[6]=f2b(v1.z); o[7]=f2b(v1.w);
      *(uint4*)&As[srow*40 + sch] = *(const uint4*)o;
    }
    #pragma unroll
    for (int p = 0; p < 4; ++p) {
      int row = srow + p*64;
      *(uint4*)&Bs[row*40 + sch] = *(const uint4*)&WTe[(size_t)row*128 + k0 + sch];
    }
    __syncthreads();
    bf16x8 af[4], bf[4];
    #pragma unroll
    for (int r = 0; r < 4; ++r) af[r] = *(const bf16x8*)&As[(r*16 + l16)*40 + quad*8];
    #pragma unroll
    for (int c = 0; c < 4; ++c) bf[c] = *(const bf16x8*)&Bs[(wn + c*16 + l16)*40 + quad*8];
    #pragma unroll
    for (int r = 0; r < 4; ++r)
      #pragma unroll
      for (int c = 0; c < 4; ++c)
        acc[r][c] = __builtin_amdgcn_mfma_f32_16x16x32_bf16(af[r], bf[c], acc[r][c], 0, 0, 0);
    __syncthreads();
  }
  u16* Xs = SH;                         // [64][264]
  #pragma unroll
  for (int c = 0; c < 4; ++c) {
    int n = wn + c*16 + l16;
    float bv = bemb[n];
    #pragma unroll
    for (int r = 0; r < 4; ++r)
      #pragma unroll
      for (int reg = 0; reg < 4; ++reg) {
        int ml = r*16 + quad*4 + reg;
        Xs[ml*264 + n] = f2b(acc[r][c][reg] + bv);
      }
  }
  __syncthreads();
  #pragma unroll
  for (int p = 0; p < 8; ++p) {
    int row = p*8 + (tid >> 5);
    int col = (tid & 31)*8;
    *(uint4*)&Xb[(size_t)(m0+row)*256 + col] = *(const uint4*)&Xs[row*264 + col];
  }
  const int tk = tid >> 2, q = tid & 3;
  float ss = 0.f;
  #pragma unroll
  for (int j = 0; j < 8; ++j) {
    uint4 v = *(const uint4*)&Xs[tk*264 + q*64 + j*8];
    const u16* u = (const u16*)&v;
    #pragma unroll
    for (int i = 0; i < 8; ++i) { float x = b2f(u[i]); ss += x*x; }
  }
  ssq[tk*4 + q] = ss;
  __syncthreads();
  if (q == 0)
    rr[tk] = rsqrtf((ssq[tk*4]+ssq[tk*4+1]+ssq[tk*4+2]+ssq[tk*4+3])*(1.f/DMODEL) + 1e-5f);
  __syncthreads();
  float r = rr[tk];
  #pragma unroll
  for (int j = 0; j < 8; ++j) {
    int idx = q*64 + j*8;
    uint4 v = *(const uint4*)&Xs[tk*264 + idx];
    const u16* u = (const u16*)&v;
    float4 w0 = *(const float4*)&nw[idx];
    float4 w1 = *(const float4*)&nw[idx+4];
    __align__(16) u16 o[8];
    o[0]=f2b(b2f(u[0])*r*w0.x); o[1]=f2b(b2f(u[1])*r*w0.y);
    o[2]=f2b(b2f(u[2])*r*w0.z); o[3]=f2b(b2f(u[3])*r*w0.w);
    o[4]=f2b(b2f(u[4])*r*w1.x); o[5]=f2b(b2f(u[5])*r*w1.y);
    o[6]=f2b(b2f(u[6])*r*w1.z); o[7]=f2b(b2f(u[7])*r*w1.w);
    *(uint4*)&XNb[(size_t)(m0+tk)*256 + idx] = *(const uint4*)o;
  }
}

// ---------------- in-proj GEMM, BK=64, global_load_lds staging + XOR-swizzled
// LDS (linear dest, inverse-swizzled source, swizzled ds_read — rule #21).
template<int K>
__global__ __launch_bounds__(256) void gemm_mfma(
    const u16* __restrict__ Ab, const u16* __restrict__ WT,
    u16* __restrict__ Cv, int N)
{
  __shared__ __align__(16) u16 SH[17408];   // staging 2*128*64=16384; Cs 128*136
  u16* As = SH;
  u16* Bs = SH + 128*64;
  const int tid = threadIdx.x;
  const int wave = tid >> 6, lane = tid & 63;
  const int quad = lane >> 4, l16 = lane & 15;
  const int bm0 = blockIdx.x*128, bn0 = blockIdx.y*128;
  const int wm = (wave & 1)*64, wn = (wave >> 1)*64;
  floatx4 acc[4][4];
  #pragma unroll
  for (int r = 0; r < 4; ++r)
    #pragma unroll
    for (int c = 0; c < 4; ++c) acc[r][c] = (floatx4){0.f,0.f,0.f,0.f};

  for (int k0 = 0; k0 < K; k0 += 64) {
    #pragma unroll
    for (int p = 0; p < 4; ++p) {
      int cid = (wave*4 + p)*64 + lane;
      int row = cid >> 3, sch = (cid & 7) ^ (row & 7);
      gload16(&Ab[(size_t)(bm0+row)*K + k0 + sch*8], As + (wave*4+p)*512);
      gload16(&WT[(size_t)(bn0+row)*K + k0 + sch*8], Bs + (wave*4+p)*512);
    }
    __syncthreads();
    #pragma unroll
    for (int ks = 0; ks < 2; ++ks) {
      bf16x8 af[4], bf[4];
      #pragma unroll
      for (int r = 0; r < 4; ++r) {
        int row = wm + r*16 + l16;
        int lch = (ks*4 + quad) ^ (row & 7);
        af[r] = *(const bf16x8*)&As[row*64 + lch*8];
      }
      #pragma unroll
      for (int c = 0; c < 4; ++c) {
        int row = wn + c*16 + l16;
        int lch = (ks*4 + quad) ^ (row & 7);
        bf[c] = *(const bf16x8*)&Bs[row*64 + lch*8];
      }
      #pragma unroll
      for (int r = 0; r < 4; ++r)
        #pragma unroll
        for (int c = 0; c < 4; ++c)
          acc[r][c] = __builtin_amdgcn_mfma_f32_16x16x32_bf16(af[r], bf[c], acc[r][c], 0, 0, 0);
    }
    __syncthreads();
  }
  u16* Cs = SH;                         // [128][136]
  #pragma unroll
  for (int c = 0; c < 4; ++c) {
    int nl = wn + c*16 + l16;
    #pragma unroll
    for (int r = 0; r < 4; ++r)
      #pragma unroll
      for (int reg = 0; reg < 4; ++reg) {
        int ml = wm + r*16 + quad*4 + reg;
        Cs[ml*136 + nl] = f2b(acc[r][c][reg]);
      }
  }
  __syncthreads();
  #pragma unroll
  for (int p = 0; p < 8; ++p) {
    int row = p*16 + (tid >> 4);
    int col = (tid & 15)*8;
    uint4 v = *(const uint4*)&Cs[row*136 + col];
    *(uint4*)&Cv[(size_t)(bm0+row)*N + bn0 + col] = v;
  }
}

// ---------------- x_dbl GEMM1 with fused causal conv+SiLU in the staging phase.
// Persists conv output xp to XPb so the scans never redo the conv.
__global__ __launch_bounds__(256) void xdblBC_k(const u16* __restrict__ XZb,
    const float* __restrict__ cw, const float* __restrict__ cb,
    const u16* __restrict__ WxT,
    float* __restrict__ BM, float* __restrict__ CM, float* __restrict__ DTR,
    u16* __restrict__ XPb)
{
  __shared__ u16 As[64*40];
  __shared__ u16 Ws[48*40];
  __shared__ float CWs[512*4];
  __shared__ float CBs[512];
  const int tid = threadIdx.x;
  const int wave = tid >> 6, lane = tid & 63;
  const int quad = lane >> 4, l16 = lane & 15;
  const int m0 = blockIdx.x*64;
  const int srow = tid >> 2, sch = (tid & 3)*8;
  const int n = m0 + srow;
  for (int e = tid; e < 2048; e += 256) CWs[e] = cw[e];
  for (int e = tid; e < 512;  e += 256) CBs[e] = cb[e];
  floatx4 acc[3];
  #pragma unroll
  for (int j = 0; j < 3; ++j) acc[j] = (floatx4){0.f,0.f,0.f,0.f};
  __syncthreads();
  const bf16x8 z8 = {0,0,0,0,0,0,0,0};
  for (int k0 = 0; k0 < DINNER; k0 += 32) {
    bf16x8 t3 = *(const bf16x8*)&XZb[(size_t)n*1024 + k0 + sch];
    bf16x8 t2 = z8, t1 = z8, t0v = z8;
    if (n >= 8)  t2  = *(const bf16x8*)&XZb[(size_t)(n-8)*1024  + k0 + sch];
    if (n >= 16) t1  = *(const bf16x8*)&XZb[(size_t)(n-16)*1024 + k0 + sch];
    if (n >= 24) t0v = *(const bf16x8*)&XZb[(size_t)(n-24)*1024 + k0 + sch];
    __align__(16) u16 outa[8];
    #pragma unroll
    for (int j = 0; j < 8; ++j) {
      int c = k0 + sch + j;
      float4 wv = *(const float4*)&CWs[c*4];
      float xc = CBs[c] + wv.x*b2f((u16)t0v[j]) + wv.y*b2f((u16)t1[j])
               + wv.z*b2f((u16)t2[j]) + wv.w*b2f((u16)t3[j]);
      outa[j] = f2b(siluf(xc));
    }
    *(uint4*)&As[srow*40 + sch] = *(const uint4*)outa;
    *(uint4*)&XPb[(size_t)n*DINNER + k0 + sch] = *(const uint4*)outa;
    if (tid < 192) {
      int wr = tid >> 2;
      *(uint4*)&Ws[wr*40 + sch] = *(const uint4*)&WxT[(size_t)wr*512 + k0 + sch];
    }
    __syncthreads();
    bf16x8 af = *(const bf16x8*)&As[(wave*16 + l16)*40 + quad*8];
    #pragma unroll
    for (int j = 0; j < 3; ++j) {
      bf16x8 bf = *(const bf16x8*)&Ws[(j*16 + l16)*40 + quad*8];
      acc[j] = __builtin_amdgcn_mfma_f32_16x16x32_bf16(af, bf, acc[j], 0, 0, 0);
    }
    __syncthreads();
  }
  const int tok0 = m0 + wave*16;
  #pragma unroll
  for (int reg = 0; reg < 4; ++reg) {
    size_t t = (size_t)(tok0 + quad*4 + reg);
    BM[t*16 + l16]  = acc[1][reg];
    CM[t*16 + l16]  = acc[2][reg];
    DTR[t*16 + l16] = acc[0][reg];
  }
}

// ---------------- scan phase A: dt projection inline, xp from XPb (prefetched).
// BM/DTR rows staged in LDS. Stores h_end, sum(dt), packed {dt,xp}.
__global__ __launch_bounds__(256) void scanA_k(const float* __restrict__ DTR,
    const u16* __restrict__ XPb, const float* __restrict__ BM,
    const float* __restrict__ Wdt, const float* __restrict__ bdt,
    const float* __restrict__ Alog, u16* __restrict__ HENDb,
    float* __restrict__ DTS, unsigned* __restrict__ DXb)
{
  __shared__ float ROWa[SEG_L*16];      // BM rows
  __shared__ float ROWb[SEG_L*16];      // DTR rows
  const int tid = threadIdx.x;
  const int seg = blockIdx.x, b = blockIdx.y, half = blockIdx.z;
  const int c = half*256 + tid;
  const int t0 = seg*SEG_L;
  const size_t base = (size_t)t0*BB + b;
  for (int idx = tid; idx < SEG_L*16; idx += 256) {
    int t = idx >> 4, j = idx & 15;
    size_t off = (base + (size_t)t*BB)*16 + j;
    ROWa[idx] = BM[off];
    ROWb[idx] = DTR[off];
  }
  float As0 = -__expf(Alog[c*16]);
  bool uni = true;
  #pragma unroll
  for (int s = 1; s < 16; ++s) {
    float Av = -__expf(Alog[c*16+s]);
    uni = uni && (fabsf(Av - As0*(float)(s+1)) <= 1e-4f*(float)(s+1));
  }
  float wdt[16];
  #pragma unroll
  for (int r = 0; r < 16; ++r) wdt[r] = Wdt[r*DINNER + c];
  const float bd = bdt[c];
  float h[16];
  #pragma unroll
  for (int s = 0; s < 16; ++s) h[s] = 0.f;
  float dts = 0.f;
  const u16* xpp = XPb + base*DINNER + c;
  __syncthreads();
  float xp = b2f(xpp[0]);
  for (int t = 0; t < SEG_L; ++t) {
    float xpn = (t+1 < SEG_L) ? b2f(xpp[(size_t)(t+1)*BB*DINNER]) : 0.f;
    float dsum = bd;
    #pragma unroll
    for (int r = 0; r < 16; ++r) dsum = fmaf(ROWb[t*16+r], wdt[r], dsum);
    float dt = (dsum > 20.f) ? dsum : __logf(1.f + __expf(dsum));
    dts += dt;
    DXb[(((size_t)(t0+t)*BB + b)*DINNER + c)] = ((unsigned)f2b(xp) << 16) | f2b(dt);
    float dtx = dt * xp;
    float dA[16];
    compute_dA(dt, As0, uni, Alog, c, dA);
    float4 r0 = *(const float4*)&ROWa[t*16 + 0];
    float4 r1 = *(const float4*)&ROWa[t*16 + 4];
    float4 r2 = *(const float4*)&ROWa[t*16 + 8];
    float4 r3 = *(const float4*)&ROWa[t*16 + 12];
    h[0]  = fmaf(dA[0],  h[0],  dtx*r0.x);
    h[1]  = fmaf(dA[1],  h[1],  dtx*r0.y);
    h[2]  = fmaf(dA[2],  h[2],  dtx*r0.z);
    h[3]  = fmaf(dA[3],  h[3],  dtx*r0.w);
    h[4]  = fmaf(dA[4],  h[4],  dtx*r1.x);
    h[5]  = fmaf(dA[5],  h[5],  dtx*r1.y);
    h[6]  = fmaf(dA[6],  h[6],  dtx*r1.z);
    h[7]  = fmaf(dA[7],  h[7],  dtx*r1.w);
    h[8]  = fmaf(dA[8],  h[8],  dtx*r2.x);
    h[9]  = fmaf(dA[9],  h[9],  dtx*r2.y);
    h[10] = fmaf(dA[10], h[10], dtx*r2.z);
    h[11] = fmaf(dA[11], h[11], dtx*r2.w);
    h[12] = fmaf(dA[12], h[12], dtx*r3.x);
    h[13] = fmaf(dA[13], h[13], dtx*r3.y);
    h[14] = fmaf(dA[14], h[14], dtx*r3.z);
    h[15] = fmaf(dA[15], h[15], dtx*r3.w);
    xp = xpn;
  }
  u16* hp = &HENDb[(((size_t)seg*BB + b)*DINNER + c)*16];
  #pragma unroll
  for (int q = 0; q < 2; ++q) {
    ushort4 v0, v1;
    v0.x = f2b(h[q*8+0]); v0.y = f2b(h[q*8+1]); v0.z = f2b(h[q*8+2]); v0.w = f2b(h[q*8+3]);
    v1.x = f2b(h[q*8+4]); v1.y = f2b(h[q*8+5]); v1.z = f2b(h[q*8+6]); v1.w = f2b(h[q*8+7]);
    *(ushort4*)&hp[q*8]     = v0;
    *(ushort4*)&hp[q*8 + 4] = v1;
  }
  DTS[((size_t)seg*BB + b)*DINNER + c] = dts;
}

// ---------------- stitch: sequential over SEG_N segments, in-place HENDb -> h0.
// Unroll-by-4 with batched prefetch: one load-stall per 4 iterations.
__global__ __launch_bounds__(256) void stitch_k(u16* __restrict__ HENDb,
    const float* __restrict__ DTS, const float* __restrict__ Alog)
{
  int g = blockIdx.x*256 + threadIdx.x;
  int b = g >> 13;
  int rem = g & 8191;          // c*16+s
  int cidx = rem >> 4;
  float A = -__expf(Alog[rem]);
  float h0 = 0.f;
  for (int k = 0; k < SEG_N; k += 4) {
    float he[4], ds[4];
    #pragma unroll
    for (int u = 0; u < 4; ++u) {
      size_t idx = (((size_t)(k+u)*BB + b) << 13) + rem;
      he[u] = b2f(HENDb[idx]);
      ds[u] = DTS[((size_t)(k+u)*BB + b)*DINNER + cidx];
    }
    #pragma unroll
    for (int u = 0; u < 4; ++u) {
      size_t idx = (((size_t)(k+u)*BB + b) << 13) + rem;
      HENDb[idx] = f2b(h0);
      h0 = fmaf(__expf(ds[u]*A), h0, he[u]);
    }
  }
}

// ---------------- scan phase C: packed {dt,xp}; BM/CM rows staged once per
// block in LDS; full scan with h0, gate, bf16 out. Prefetch dx/zg one step.
__global__ __launch_bounds__(256) void scanC_k(const unsigned* __restrict__ DXb,
    const u16* __restrict__ XZb, const float* __restrict__ BM, const float* __restrict__ CM,
    const float* __restrict__ Alog, const float* __restrict__ Dp,
    const u16* __restrict__ H0b, u16* __restrict__ YGb)
{
  __shared__ float ROWa[SEG_L*16];      // BM rows
  __shared__ float ROWc[SEG_L*16];      // CM rows
  const int tid = threadIdx.x;
  const int seg = blockIdx.x, b = blockIdx.y, half = blockIdx.z;
  const int c = half*256 + tid;
  const int t0 = seg*SEG_L;
  const size_t base = (size_t)t0*BB + b;
  for (int idx = tid; idx < SEG_L*16; idx += 256) {
    int t = idx >> 4, j = idx & 15;
    size_t off = (base + (size_t)t*BB)*16 + j;
    ROWa[idx] = BM[off];
    ROWc[idx] = CM[off];
  }
  float As0 = -__expf(Alog[c*16]);
  bool uni = true;
  #pragma unroll
  for (int s = 1; s < 16; ++s) {
    float Av = -__expf(Alog[c*16+s]);
    uni = uni && (fabsf(Av - As0*(float)(s+1)) <= 1e-4f*(float)(s+1));
  }
  float h[16];
  const u16* hp = &H0b[(((size_t)seg*BB + b)*DINNER + c)*16];
  #pragma unroll
  for (int q = 0; q < 4; ++q) {
    ushort4 hv = *(const ushort4*)&hp[q*4];
    h[q*4+0]=b2f(hv.x); h[q*4+1]=b2f(hv.y); h[q*4+2]=b2f(hv.z); h[q*4+3]=b2f(hv.w);
  }
  const float Dv = Dp[c];
  const unsigned* dxp = DXb + base*DINNER + c;
  const u16* zp  = XZb + base*1024 + DINNER + c;
  u16*       ygp = YGb + base*DINNER + c;
  __syncthreads();
  unsigned dx = dxp[0];
  float zg = b2f(zp[0]);
  for (int t = 0; t < SEG_L; ++t) {
    unsigned dxn = 0; float zgn = 0.f;
    if (t+1 < SEG_L) {
      dxn = dxp[(size_t)(t+1)*BB*DINNER];
      zgn = b2f(zp[(size_t)(t+1)*BB*1024]);
    }
    float dt = __uint_as_float(dx << 16);
    float xp = __uint_as_float(dx & 0xffff0000u);
    float dtx = dt * xp;
    float dA[16];
    compute_dA(dt, As0, uni, Alog, c, dA);
    float4 ra0 = *(const float4*)&ROWa[t*16 + 0];
    float4 ra1 = *(const float4*)&ROWa[t*16 + 4];
    float4 ra2 = *(const float4*)&ROWa[t*16 + 8];
    float4 ra3 = *(const float4*)&ROWa[t*16 + 12];
    float4 rc0 = *(const float4*)&ROWc[t*16 + 0];
    float4 rc1 = *(const float4*)&ROWc[t*16 + 4];
    float4 rc2 = *(const float4*)&ROWc[t*16 + 8];
    float4 rc3 = *(const float4*)&ROWc[t*16 + 12];
    float y0 = 0.f, y1 = 0.f, y2 = 0.f, y3 = 0.f;
    h[0]  = fmaf(dA[0],  h[0],  dtx*ra0.x); y0 = fmaf(h[0],  rc0.x, y0);
    h[1]  = fmaf(dA[1],  h[1],  dtx*ra0.y); y1 = fmaf(h[1],  rc0.y, y1);
    h[2]  = fmaf(dA[2],  h[2],  dtx*ra0.z); y2 = fmaf(h[2],  rc0.z, y2);
    h[3]  = fmaf(dA[3],  h[3],  dtx*ra0.w); y3 = fmaf(h[3],  rc0.w, y3);
    h[4]  = fmaf(dA[4],  h[4],  dtx*ra1.x); y0 = fmaf(h[4],  rc1.x, y0);
    h[5]  = fmaf(dA[5],  h[5],  dtx*ra1.y); y1 = fmaf(h[5],  rc1.y, y1);
    h[6]  = fmaf(dA[6],  h[6],  dtx*ra1.z); y2 = fmaf(h[6],  rc1.z, y2);
    h[7]  = fmaf(dA[7],  h[7],  dtx*ra1.w); y3 = fmaf(h[7],  rc1.w, y3);
    h[8]  = fmaf(dA[8],  h[8],  dtx*ra2.x); y0 = fmaf(h[8],  rc2.x, y0);
    h[9]  = fmaf(dA[9],  h[9],  dtx*ra2.y); y1 = fmaf(h[9],  rc2.y, y1);
    h[10] = fmaf(dA[10], h[10], dtx*ra2.z); y2 = fmaf(h[10], rc2.z, y2);
    h[11] = fmaf(dA[11], h[11], dtx*ra2.w); y3 = fmaf(h[11], rc2.w, y3);
    h[12] = fmaf(dA[12], h[12], dtx*ra3.x); y0 = fmaf(h[12], rc3.x, y0);
    h[13] = fmaf(dA[13], h[13], dtx*ra3.y); y1 = fmaf(h[13], rc3.y, y1);
    h[14] = fmaf(dA[14], h[14], dtx*ra3.z); y2 = fmaf(h[14], rc3.z, y2);
    h[15] = fmaf(dA[15], h[15], dtx*ra3.w); y3 = fmaf(h[15], rc3.w, y3);
    float y = (y0+y1) + (y2+y3);
    ygp[(size_t)t*BB*DINNER] = f2b((y + xp*Dv) * siluf(zg));
    dx = dxn; zg = zgn;
  }
}

// ---------------- fused out-proj (BK=64) + residual + action head + log-prob
__global__ __launch_bounds__(256) void outhead_k(const u16* __restrict__ YGb,
    const u16* __restrict__ WTo, const u16* __restrict__ Xb,
    const u16* __restrict__ WhT, const float* __restrict__ bh,
    const float* __restrict__ lstd, const float* __restrict__ a,
    float* __restrict__ out)
{
  __shared__ u16 SH[(64+256)*72];
  u16* As = SH;
  u16* Bs = SH + 64*72;
  const int tid = threadIdx.x;
  const int wave = tid >> 6, lane = tid & 63;
  const int quad = lane >> 4, l16 = lane & 15;
  const int m0 = blockIdx.x*64;
  const int n0 = wave*64;
  const int srow = tid >> 3, sch = (tid & 7)*8;
  floatx4 acc[4][4];
  #pragma unroll
  for (int r = 0; r < 4; ++r)
    #pragma unroll
    for (int c = 0; c < 4; ++c) acc[r][c] = (floatx4){0.f,0.f,0.f,0.f};

  for (int k0 = 0; k0 < DINNER; k0 += 64) {
    #pragma unroll
    for (int p = 0; p < 2; ++p) {
      int row = srow + p*32;
      *(uint4*)&As[row*72 + sch] = *(const uint4*)&YGb[(size_t)(m0+row)*DINNER + k0 + sch];
    }
    #pragma unroll
    for (int p = 0; p < 8; ++p) {
      int row = srow + p*32;
      *(uint4*)&Bs[row*72 + sch] = *(const uint4*)&WTo[(size_t)row*DINNER + k0 + sch];
    }
    __syncthreads();
    #pragma unroll
    for (int ks = 0; ks < 2; ++ks) {
      bf16x8 af[4], bf[4];
      #pragma unroll
      for (int r = 0; r < 4; ++r)
        af[r] = *(const bf16x8*)&As[(r*16 + l16)*72 + ks*32 + quad*8];
      #pragma unroll
      for (int c = 0; c < 4; ++c)
        bf[c] = *(const bf16x8*)&Bs[(n0 + c*16 + l16)*72 + ks*32 + quad*8];
      #pragma unroll
      for (int r = 0; r < 4; ++r)
        #pragma unroll
        for (int c = 0; c < 4; ++c)
          acc[r][c] = __builtin_amdgcn_mfma_f32_16x16x32_bf16(af[r], bf[c], acc[r][c], 0, 0, 0);
    }
    __syncthreads();
  }
  u16* Xs = SH;                         // [64][264]
  #pragma unroll
  for (int p = 0; p < 8; ++p) {
    int row = p*8 + (tid >> 5);
    int col = (tid & 31)*8;
    *(uint4*)&Xs[row*264 + col] = *(const uint4*)&Xb[(size_t)(m0+row)*256 + col];
  }
  __syncthreads();
  #pragma unroll
  for (int c = 0; c < 4; ++c) {
    int n = n0 + c*16 + l16;
    #pragma unroll
    for (int r = 0; r < 4; ++r) {
      #pragma unroll
      for (int reg = 0; reg < 4; ++reg) {
        int ml = r*16 + quad*4 + reg;
        Xs[ml*264 + n] = f2b(acc[r][c][reg] + b2f(Xs[ml*264 + n]));
      }
    }
  }
  __syncthreads();
  floatx4 mu[2];
  mu[0] = (floatx4){0.f,0.f,0.f,0.f};
  mu[1] = (floatx4){0.f,0.f,0.f,0.f};
  #pragma unroll
  for (int k0 = 0; k0 < DMODEL; k0 += 32) {
    bf16x8 axf = *(const bf16x8*)&Xs[(wave*16 + l16)*264 + k0 + quad*8];
    #pragma unroll
    for (int nt = 0; nt < 2; ++nt) {
      bf16x8 bwf = *(const bf16x8*)(WhT + (size_t)(nt*16 + l16)*DMODEL + k0 + quad*8);
      mu[nt] = __builtin_amdgcn_mfma_f32_16x16x32_bf16(axf, bwf, mu[nt], 0, 0, 0);
    }
  }
  float ls0 = lstd[l16],      els0 = __expf(-ls0), bh0 = bh[l16];
  float ls1 = lstd[16 + l16], els1 = __expf(-ls1), bh1 = bh[16 + l16];
  #pragma unroll
  for (int reg = 0; reg < 4; ++reg) {
    int tok = m0 + wave*16 + quad*4 + reg;
    float m0v = mu[0][reg] + bh0;
    float m1v = mu[1][reg] + bh1;
    float z0 = (a[(size_t)tok*32 + l16]      - m0v) * els0;
    float z1 = (a[(size_t)tok*32 + 16 + l16] - m1v) * els1;
    float t = (-0.5f*z0*z0 - ls0) + (-0.5f*z1*z1 - ls1) - 2.f*0.91893853320467274f;
    t += __shfl_xor(t, 1);
    t += __shfl_xor(t, 2);
    t += __shfl_xor(t, 4);
    t += __shfl_xor(t, 8);
    if (l16 == 0) out[tok] = t;
  }
}

extern "C" void kernel_launch(void* const* d_in, const int* in_sizes, int n_in,
                              void* d_out, int out_size, void* d_ws, size_t ws_size,
                              hipStream_t stream)
{
  const float* s    = (const float*)d_in[0];
  const float* a    = (const float*)d_in[1];
  const float* Wemb = (const float*)d_in[2];
  const float* bemb = (const float*)d_in[3];
  const float* nw   = (const float*)d_in[4];
  const float* Win  = (const float*)d_in[5];
  const float* cw   = (const float*)d_in[6];
  const float* cb   = (const float*)d_in[7];
  const float* Wx   = (const float*)d_in[8];
  const float* Wdt  = (const float*)d_in[9];
  const float* bdt  = (const float*)d_in[10];
  const float* Alog = (const float*)d_in[11];
  const float* Dp   = (const float*)d_in[12];
  const float* Wout = (const float*)d_in[13];
  const float* Wh   = (const float*)d_in[14];
  const float* bh   = (const float*)d_in[15];
  const float* lstd = (const float*)d_in[16];

  // -------- workspace layout (~140 MB)
  u16*   Xb   = (u16*)d_ws;                         // NTOK*256 bf16 (emb resid)
  u16*   XZb  = Xb  + (size_t)NTOK*DMODEL;          // NTOK*1024 bf16 [xp|z]
  u16*   XNb  = XZb + (size_t)NTOK*1024;            // NTOK*256 bf16
  u16*   YGb  = XNb + (size_t)NTOK*DMODEL;          // NTOK*512 bf16
  u16*   WTe  = YGb + (size_t)NTOK*DINNER;          // 256*128
  u16*   WTi  = WTe + 256*128;                      // 1024*256
  u16*   WTo  = WTi + 1024*256;                     // 256*512
  u16*   WxT  = WTo + 256*512;                      // 48*512
  u16*   WhT  = WxT + 48*512;                       // 32*256
  u16*   HENDb= WhT + 32*256;                       // NSEG*8*512*16 bf16 (SEG_N used)
  u16*   XPb  = HENDb + (size_t)NSEG*BB*DINNER*16;  // NTOK*512 bf16 (conv+silu xp)
  unsigned* DXb = (unsigned*)(XPb + (size_t)NTOK*DINNER); // NTOK*512 u32 {xp,dt}
  float* BM   = (float*)(DXb + (size_t)NTOK*DINNER);// NTOK*16 fp32
  float* CM   = BM + (size_t)NTOK*16;               // NTOK*16 fp32
  float* DTR  = CM + (size_t)NTOK*16;               // NTOK*16 fp32
  float* DTS  = DTR + (size_t)NTOK*16;              // NSEG*8*512 fp32
  float* out  = (float*)d_out;

  prepWTe_k     <<<128,         256, 0, stream>>>(Wemb, WTe);
  embnorm_k     <<<480,         256, 0, stream>>>(s, WTe, bemb, nw,
                                                  Win, Wout, Wx, Wh,
                                                  Xb, XNb, WTi, WTo, WxT, WhT);
  gemm_mfma<256><<<dim3(128,8), 256, 0, stream>>>(XNb, WTi, XZb, 1024);
  xdblBC_k      <<<256,         256, 0, stream>>>(XZb, cw, cb, WxT, BM, CM, DTR, XPb);
  scanA_k       <<<dim3(SEG_N,BB,2), 256, 0, stream>>>(DTR, XPb, BM, Wdt, bdt,
                                                       Alog, HENDb, DTS, DXb);
  stitch_k      <<<256,         256, 0, stream>>>(HENDb, DTS, Alog);
  scanC_k       <<<dim3(SEG_N,BB,2), 256, 0, stream>>>(DXb, XZb, BM, CM,
                                                       Alog, Dp, HENDb, YGb);
  outhead_k     <<<256,         256, 0, stream>>>(YGb, WTo, Xb, WhT, bh, lstd, a, out);
}